// Round 5
// baseline (196.912 us; speedup 1.0000x reference)
//
#include <hip/hip_runtime.h>
#include <hip/hip_bf16.h>

#define B 128
#define N 32
#define DO 128
#define NA 16
#define H 4
#define DK 64
#define DV 64
#define LN_EPS 1e-5f
#define NEG_SLOPE 0.01f

__device__ __forceinline__ float leaky(float x) {
    return x >= 0.f ? x : NEG_SLOPE * x;
}

// ---------------------------------------------------------------------------
// kT: repack Wq/Wk/Wv -> wT[(h*3+m)*8192 + dc*256 + e*4 + j] = W[h][4dc+j][e]
// so a lane (e) reads float4 over d, fully coalesced across lanes.
// ---------------------------------------------------------------------------
__global__ __launch_bounds__(256) void kT(
    const float* __restrict__ Wk, const float* __restrict__ Wq,
    const float* __restrict__ Wv, float* __restrict__ wT)
{
    const int blk = blockIdx.x;          // 0..11 = h*3+m
    const int h = blk / 3, m = blk % 3;
    const float* src = (m == 0 ? Wq : (m == 1 ? Wk : Wv)) + h * 128 * 64;
    float* dst = wT + blk * 8192;
    for (int idx = threadIdx.x; idx < 8192; idx += 256) {
        const int dc = idx >> 8, r = idx & 255, e = r >> 2, j = r & 3;
        dst[idx] = src[(dc * 4 + j) * 64 + e];
    }
}

// ---------------------------------------------------------------------------
// Kernel A: 512 blocks x 128 threads; 8 rows per block; float4 LDS reads
// ---------------------------------------------------------------------------
__global__ __launch_bounds__(128) void kA(
    const float* __restrict__ states, const float* __restrict__ policies,
    const float* __restrict__ actions, const float* __restrict__ W_se,
    const float* __restrict__ b_se, const float* __restrict__ W_sape,
    const float* __restrict__ b_sape,
    float* __restrict__ se, float* __restrict__ xa, float* __restrict__ xp)
{
    const int row0 = blockIdx.x * 8;
    const int t    = threadIdx.x;

    __shared__ float s_rows[8][128];
    __shared__ float a_rows[8][16];
    __shared__ float p_rows[8][16];
    __shared__ float tail[16][128];   // W_sape rows 128..143

    {
        const float4* src = (const float4*)(states + row0 * 128);
        float4* dst = (float4*)&s_rows[0][0];
        dst[t]       = src[t];
        dst[t + 128] = src[t + 128];
        const int r = t >> 4, d = t & 15;
        a_rows[r][d] = actions[(row0 + r) * 16 + d];
        p_rows[r][d] = policies[(row0 + r) * 16 + d];
        const float4* tsrc = (const float4*)(W_sape + 128 * 128);
        float4* tdst = (float4*)&tail[0][0];
        #pragma unroll
        for (int k = 0; k < 4; k++) tdst[t + k * 128] = tsrc[t + k * 128];
    }
    __syncthreads();

    float acc_se[8] = {0,0,0,0,0,0,0,0};
    float acc_sp[8] = {0,0,0,0,0,0,0,0};
    #pragma unroll 2
    for (int dc = 0; dc < 32; dc++) {
        float wse[4], wsp[4];
        #pragma unroll
        for (int j = 0; j < 4; j++) {
            wse[j] = W_se[(dc * 4 + j) * 128 + t];
            wsp[j] = W_sape[(dc * 4 + j) * 128 + t];
        }
        #pragma unroll
        for (int r = 0; r < 8; r++) {
            const float4 s4 = *(const float4*)&s_rows[r][dc * 4];
            acc_se[r] += s4.x * wse[0] + s4.y * wse[1] + s4.z * wse[2] + s4.w * wse[3];
            acc_sp[r] += s4.x * wsp[0] + s4.y * wsp[1] + s4.z * wsp[2] + s4.w * wsp[3];
        }
    }
    const float bse = b_se[t], bsp = b_sape[t];
    #pragma unroll
    for (int r = 0; r < 8; r++) {
        float aa = bsp + acc_sp[r];
        float pp = aa;
        #pragma unroll
        for (int d = 0; d < 16; d++) {
            const float wv = tail[d][t];
            aa += a_rows[r][d] * wv;
            pp += p_rows[r][d] * wv;
        }
        se[(row0 + r) * 128 + t] = leaky(bse + acc_se[r]);
        xa[(row0 + r) * 128 + t] = leaky(aa);
        xp[(row0 + r) * 128 + t] = leaky(pp);
    }
}

// ---------------------------------------------------------------------------
// Kernel B (per b,h; 512 threads; LDS 54,272B): all hot loops float4
// ---------------------------------------------------------------------------
#define RS 68

__global__ __launch_bounds__(512, 6) void kB(
    const float* __restrict__ se, const float* __restrict__ xa,
    const float* __restrict__ xp, const float* __restrict__ wT,
    const float* __restrict__ W_f1, const float* __restrict__ ln_g,
    float* __restrict__ w_out,
    float* __restrict__ SG, float* __restrict__ DG,
    float* __restrict__ sumS, float* __restrict__ sumS2,
    float* __restrict__ sumD, float* __restrict__ sumD2,
    float* __restrict__ dotSD, float* __restrict__ GW)
{
    const int bh = blockIdx.x;
    const int b  = bh >> 2;
    const int h  = bh & 3;
    const int t  = threadIdx.x;

    __shared__ float bufA[N * 128];   // se -> xp -> Wg[e][c]
    __shared__ float bufB[N * 128];   // xa; [0,2048) becomes ava[i*64+e]
    __shared__ float q_s[N * RS];     // q -> S
    __shared__ float k_s[N * RS];     // k -> diff
    __shared__ float sc[N * 32];      // scores -> w

    for (int idx = t; idx < N * 32; idx += 512) {
        ((float4*)bufA)[idx] = ((const float4*)(se + b * N * 128))[idx];
        ((float4*)bufB)[idx] = ((const float4*)(xa + b * N * 128))[idx];
    }
    __syncthreads();

    const float4* WqT = (const float4*)(wT + (h * 3 + 0) * 8192);
    const float4* WkT = (const float4*)(wT + (h * 3 + 1) * 8192);
    const float4* WvT = (const float4*)(wT + (h * 3 + 2) * 8192);

    // stage 1: 4 rows/thread; float4 weights (coalesced) + float4 row broadcasts
    const int e  = t & 63;
    const int i0 = (t >> 6) * 4;
    float aq[4] = {0,0,0,0}, ak[4] = {0,0,0,0}, av[4] = {0,0,0,0};
    #pragma unroll 2
    for (int dc = 0; dc < 32; dc++) {
        const float4 wq = WqT[dc * 64 + e];
        const float4 wk = WkT[dc * 64 + e];
        const float4 wv = WvT[dc * 64 + e];
        #pragma unroll
        for (int r = 0; r < 4; r++) {
            const float4 sA = *(const float4*)&bufA[(i0 + r) * 128 + dc * 4];
            const float4 sB = *(const float4*)&bufB[(i0 + r) * 128 + dc * 4];
            aq[r] += sA.x * wq.x + sA.y * wq.y + sA.z * wq.z + sA.w * wq.w;
            ak[r] += sA.x * wk.x + sA.y * wk.y + sA.z * wk.z + sA.w * wk.w;
            av[r] += sB.x * wv.x + sB.y * wv.y + sB.z * wv.z + sB.w * wv.w;
        }
    }
    #pragma unroll
    for (int r = 0; r < 4; r++) {
        q_s[(i0 + r) * RS + e] = aq[r];
        k_s[(i0 + r) * RS + e] = ak[r];
    }
    __syncthreads();

    // stage 2: ava -> bufB[0:2048), xp -> bufA, scores
    #pragma unroll
    for (int r = 0; r < 4; r++) bufB[(i0 + r) * 64 + e] = av[r];
    for (int idx = t; idx < N * 32; idx += 512)
        ((float4*)bufA)[idx] = ((const float4*)(xp + b * N * 128))[idx];
    for (int o = t; o < N * N; o += 512) {
        const int i = o >> 5, j = o & 31;
        float a = 0.f;
        #pragma unroll
        for (int e4 = 0; e4 < 16; e4++) {
            const float4 qv = *(const float4*)&q_s[i * RS + e4 * 4];
            const float4 kv = *(const float4*)&k_s[j * RS + e4 * 4];
            a += qv.x * kv.x + qv.y * kv.y + qv.z * kv.z + qv.w * kv.w;
        }
        sc[i * 32 + j] = a * 0.125f;
    }
    __syncthreads();

    // stage 2b: softmax, 16 lanes per row
    {
        const int i = t >> 4, l = t & 15;
        float v0 = sc[i * 32 + l], v1 = sc[i * 32 + 16 + l];
        float mx = fmaxf(v0, v1);
        #pragma unroll
        for (int m = 8; m; m >>= 1) mx = fmaxf(mx, __shfl_xor(mx, m));
        float e0 = __expf(v0 - mx), e1 = __expf(v1 - mx);
        float sum = e0 + e1;
        #pragma unroll
        for (int m = 8; m; m >>= 1) sum += __shfl_xor(sum, m);
        const float inv = 1.f / sum;
        e0 *= inv; e1 *= inv;
        sc[i * 32 + l]      = e0;
        sc[i * 32 + 16 + l] = e1;
        w_out[(bh * N + i) * N + l]      = e0;
        w_out[(bh * N + i) * N + 16 + l] = e1;
    }
    __syncthreads();

    // stage 3: avp -> diff (k_s); S = w@ava (q_s)
    float ap[4] = {0,0,0,0};
    #pragma unroll 2
    for (int dc = 0; dc < 32; dc++) {
        const float4 wv = WvT[dc * 64 + e];
        #pragma unroll
        for (int r = 0; r < 4; r++) {
            const float4 sA = *(const float4*)&bufA[(i0 + r) * 128 + dc * 4];
            ap[r] += sA.x * wv.x + sA.y * wv.y + sA.z * wv.z + sA.w * wv.w;
        }
    }
    float sa[4] = {0,0,0,0};
    #pragma unroll
    for (int kc = 0; kc < 8; kc++) {
        const float4 s0 = *(const float4*)&sc[(i0 + 0) * 32 + kc * 4];
        const float4 s1 = *(const float4*)&sc[(i0 + 1) * 32 + kc * 4];
        const float4 s2 = *(const float4*)&sc[(i0 + 2) * 32 + kc * 4];
        const float4 s3 = *(const float4*)&sc[(i0 + 3) * 32 + kc * 4];
        const float a0 = bufB[(kc * 4 + 0) * 64 + e];
        const float a1 = bufB[(kc * 4 + 1) * 64 + e];
        const float a2 = bufB[(kc * 4 + 2) * 64 + e];
        const float a3 = bufB[(kc * 4 + 3) * 64 + e];
        sa[0] += s0.x * a0 + s0.y * a1 + s0.z * a2 + s0.w * a3;
        sa[1] += s1.x * a0 + s1.y * a1 + s1.z * a2 + s1.w * a3;
        sa[2] += s2.x * a0 + s2.y * a1 + s2.z * a2 + s2.w * a3;
        sa[3] += s3.x * a0 + s3.y * a1 + s3.z * a2 + s3.w * a3;
    }
    #pragma unroll
    for (int r = 0; r < 4; r++) {
        k_s[(i0 + r) * RS + e] = ap[r] - bufB[(i0 + r) * 64 + e];
        q_s[(i0 + r) * RS + e] = sa[r];
    }
    __syncthreads();

    // stage 3b: Wg -> bufA (xp dead)
    for (int idx = t; idx < 4096; idx += 512) {
        const int ee = idx >> 6, c = idx & 63;
        bufA[idx] = ln_g[h * 64 + ee] * W_f1[(h * 64 + ee) * 64 + c];
    }
    __syncthreads();

    // stage 4: row sums (t<64) + GW column sums (64<=t<128)
    if (t < 64) {
        const int r = t & 31;
        const float* src = (t < 32) ? (q_s + r * RS) : (k_s + r * RS);
        float s1 = 0.f, s2 = 0.f;
        #pragma unroll
        for (int e4 = 0; e4 < 16; e4++) {
            const float4 v = *(const float4*)&src[e4 * 4];
            s1 += v.x + v.y + v.z + v.w;
            s2 += v.x * v.x + v.y * v.y + v.z * v.z + v.w * v.w;
        }
        if (t < 32) { sumS[bh * N + r] = s1; sumS2[bh * N + r] = s2; }
        else        { sumD[bh * N + r] = s1; sumD2[bh * N + r] = s2; }
    } else if (t < 128) {
        const int c = t - 64;
        float g = 0.f;
        #pragma unroll 8
        for (int ee = 0; ee < 64; ee++) g += bufA[ee * 64 + c];
        GW[h * 64 + c] = g;
    }

    // stage 5: dotSD
    for (int o = t; o < N * N; o += 512) {
        const int i = o >> 5, j = o & 31;
        float a = 0.f;
        #pragma unroll
        for (int e4 = 0; e4 < 16; e4++) {
            const float4 sv = *(const float4*)&q_s[i * RS + e4 * 4];
            const float4 dv = *(const float4*)&k_s[j * RS + e4 * 4];
            a += sv.x * dv.x + sv.y * dv.y + sv.z * dv.z + sv.w * dv.w;
        }
        dotSD[(bh * N + i) * N + j] = a;
    }

    // stage 6: SG = S@Wg, DG = diff@Wg; src rows read as float4
    for (int qo = t; qo < 1024; qo += 512) {
        const int isS = (qo < 512) ? 1 : 0;
        const int idx = qo & 511;
        const int r   = idx >> 4;
        const int c4  = (idx & 15) << 2;
        const float* src = isS ? (q_s + r * RS) : (k_s + r * RS);
        float4 acc = {0.f, 0.f, 0.f, 0.f};
        #pragma unroll
        for (int e4 = 0; e4 < 16; e4++) {
            const float4 s4 = *(const float4*)&src[e4 * 4];
            const float* sp = (const float*)&s4;
            #pragma unroll
            for (int q = 0; q < 4; q++) {
                const float s = sp[q];
                const float4 wv = *(const float4*)&bufA[(e4 * 4 + q) * 64 + c4];
                acc.x += s * wv.x; acc.y += s * wv.y;
                acc.z += s * wv.z; acc.w += s * wv.w;
            }
        }
        float* dst = (isS ? SG : DG) + (bh * N + r) * 64 + c4;
        *(float4*)dst = acc;
    }
}

// ---------------------------------------------------------------------------
// Kernel C (512 blocks: b x 4 i-groups of 8; 256 threads)
// ---------------------------------------------------------------------------
__global__ __launch_bounds__(256) void kC(
    const float* __restrict__ SG, const float* __restrict__ DG,
    const float* __restrict__ sumS, const float* __restrict__ sumS2,
    const float* __restrict__ sumD, const float* __restrict__ sumD2,
    const float* __restrict__ dotSD, const float* __restrict__ w_all,
    const float* __restrict__ GW, const float* __restrict__ ln_b,
    const float* __restrict__ W_f1, const float* __restrict__ W_f2,
    float* __restrict__ value)
{
    const int blk = blockIdx.x;
    const int b   = blk >> 2;
    const int i0  = (blk & 3) * 8;
    const int t   = threadIdx.x;

    __shared__ float SGs[8][256];
    __shared__ float GWs[256];
    __shared__ float BWs[64], wf2s[64];
    __shared__ float bwp[4][64];
    __shared__ float w_s[4][8][32];
    __shared__ float mu_s[4][8][32];
    __shared__ float inv_s[4][8][32];

    {
        const int c = t & 63, qq = t >> 6;
        float bacc = 0.f;
        #pragma unroll 4
        for (int r = 0; r < 64; r++)
            bacc += ln_b[qq * 64 + r] * W_f1[(qq * 64 + r) * 64 + c];
        bwp[qq][c] = bacc;
    }

    GWs[t] = GW[t];
    if (t < 64) wf2s[t] = W_f2[t];
    for (int idx4 = t; idx4 < 512; idx4 += 256) {
        const int ii  = idx4 >> 6;
        const int hc4 = idx4 & 63;
        const int hh  = hc4 >> 4, c4 = (hc4 & 15) * 4;
        ((float4*)&SGs[ii][0])[hc4] =
            *(const float4*)&SG[((b * 4 + hh) * 32 + i0 + ii) * 64 + c4];
    }
    for (int idx = t; idx < 1024; idx += 256) {
        const int hh = idx >> 8, ii = (idx >> 5) & 7, j = idx & 31;
        const int hi = (b * 4 + hh) * 32 + (i0 + ii);
        const int hj = (b * 4 + hh) * 32 + j;
        const float wv  = w_all[hi * 32 + j];
        const float dsd = dotSD[hi * 32 + j];
        const float mu  = (sumS[hi] + wv * sumD[hj]) * (1.f / 64.f);
        const float e2  = (sumS2[hi] + 2.f * wv * dsd + wv * wv * sumD2[hj]) * (1.f / 64.f);
        const float var = fmaxf(e2 - mu * mu, 0.f);
        w_s[hh][ii][j]   = wv;
        mu_s[hh][ii][j]  = mu;
        inv_s[hh][ii][j] = rsqrtf(var + LN_EPS);
    }
    __syncthreads();
    if (t < 64) BWs[t] = bwp[0][t] + bwp[1][t] + bwp[2][t] + bwp[3][t];
    __syncthreads();

    const int w0 = t >> 6;
    const int e  = t & 63;
    const float GW0 = GWs[e],       GW1 = GWs[64 + e];
    const float GW2 = GWs[128 + e], GW3 = GWs[192 + e];
    const float bwr = BWs[e], f2 = wf2s[e];
    const float* DGb = DG + b * H * N * 64;

    for (int jb = 0; jb < 8; jb++) {
        const int j = jb * 4 + w0;
        const float d0 = DGb[(0 * 32 + j) * 64 + e];
        const float d1 = DGb[(1 * 32 + j) * 64 + e];
        const float d2 = DGb[(2 * 32 + j) * 64 + e];
        const float d3 = DGb[(3 * 32 + j) * 64 + e];
        #pragma unroll
        for (int ii = 0; ii < 8; ii++) {
            float z = bwr;
            z += inv_s[0][ii][j] * (SGs[ii][e]       + w_s[0][ii][j] * d0 - mu_s[0][ii][j] * GW0);
            z += inv_s[1][ii][j] * (SGs[ii][64 + e]  + w_s[1][ii][j] * d1 - mu_s[1][ii][j] * GW1);
            z += inv_s[2][ii][j] * (SGs[ii][128 + e] + w_s[2][ii][j] * d2 - mu_s[2][ii][j] * GW2);
            z += inv_s[3][ii][j] * (SGs[ii][192 + e] + w_s[3][ii][j] * d3 - mu_s[3][ii][j] * GW3);
            float p = leaky(z) * f2;
            #pragma unroll
            for (int m = 32; m; m >>= 1) p += __shfl_xor(p, m);
            if (e == 0) value[(b * 32 + i0 + ii) * 32 + j] = p;
        }
    }
}

extern "C" void kernel_launch(void* const* d_in, const int* in_sizes, int n_in,
                              void* d_out, int out_size, void* d_ws, size_t ws_size,
                              hipStream_t stream)
{
    const float* states   = (const float*)d_in[0];
    const float* policies = (const float*)d_in[1];
    const float* actions  = (const float*)d_in[2];
    const float* W_se     = (const float*)d_in[3];
    const float* b_se     = (const float*)d_in[4];
    const float* W_sape   = (const float*)d_in[5];
    const float* b_sape   = (const float*)d_in[6];
    const float* Wk       = (const float*)d_in[7];
    const float* Wq       = (const float*)d_in[8];
    const float* Wv       = (const float*)d_in[9];
    const float* ln_g     = (const float*)d_in[10];
    const float* ln_b     = (const float*)d_in[11];
    const float* W_f1     = (const float*)d_in[12];
    const float* W_f2     = (const float*)d_in[13];

    float* out_value = (float*)d_out;
    float* out_w     = out_value + B * N * N;

    float* ws    = (float*)d_ws;
    float* se    = ws;
    float* xa    = se    + B * N * 128;
    float* xp    = xa    + B * N * 128;
    float* SG    = xp    + B * N * 128;
    float* DG    = SG    + B * H * N * 64;
    float* sumS  = DG    + B * H * N * 64;
    float* sumS2 = sumS  + B * H * N;
    float* sumD  = sumS2 + B * H * N;
    float* sumD2 = sumD  + B * H * N;
    float* dotSD = sumD2 + B * H * N;
    float* GW    = dotSD + B * H * N * N;
    float* wT    = GW    + 256;            // 3*H*128*64 = 98304 floats

    kT<<<12, 256, 0, stream>>>(Wk, Wq, Wv, wT);
    kA<<<512, 128, 0, stream>>>(states, policies, actions, W_se, b_se,
                                W_sape, b_sape, se, xa, xp);
    kB<<<B * H, 512, 0, stream>>>(se, xa, xp, wT, W_f1, ln_g, out_w,
                                  SG, DG, sumS, sumS2, sumD, sumD2, dotSD, GW);
    kC<<<512, 256, 0, stream>>>(SG, DG, sumS, sumS2, sumD, sumD2, dotSD,
                                out_w, GW, ln_b, W_f1, W_f2, out_value);
}

// Round 6
// 186.928 us; speedup vs baseline: 1.0534x; 1.0534x over previous
//
#include <hip/hip_runtime.h>
#include <hip/hip_bf16.h>

#define B 128
#define N 32
#define DO 128
#define NA 16
#define H 4
#define DK 64
#define DV 64
#define LN_EPS 1e-5f
#define NEG_SLOPE 0.01f

__device__ __forceinline__ float leaky(float x) {
    return x >= 0.f ? x : NEG_SLOPE * x;
}

// ---------------------------------------------------------------------------
// kT: repack Wq/Wk/Wv -> wT[(h*3+m)*8192 + dc*256 + e*4 + j] = W[h][4dc+j][e]
// ---------------------------------------------------------------------------
__global__ __launch_bounds__(256) void kT(
    const float* __restrict__ Wk, const float* __restrict__ Wq,
    const float* __restrict__ Wv, float* __restrict__ wT)
{
    const int blk = blockIdx.x;          // 0..11 = h*3+m
    const int h = blk / 3, m = blk % 3;
    const float* src = (m == 0 ? Wq : (m == 1 ? Wk : Wv)) + h * 128 * 64;
    float* dst = wT + blk * 8192;
    for (int idx = threadIdx.x; idx < 8192; idx += 256) {
        const int dc = idx >> 8, r = idx & 255, e = r >> 2, j = r & 3;
        dst[idx] = src[(dc * 4 + j) * 64 + e];
    }
}

// ---------------------------------------------------------------------------
// Kernel A: 512 blocks x 128 threads; 8 rows per block
// ---------------------------------------------------------------------------
__global__ __launch_bounds__(128) void kA(
    const float* __restrict__ states, const float* __restrict__ policies,
    const float* __restrict__ actions, const float* __restrict__ W_se,
    const float* __restrict__ b_se, const float* __restrict__ W_sape,
    const float* __restrict__ b_sape,
    float* __restrict__ se, float* __restrict__ xa, float* __restrict__ xp)
{
    const int row0 = blockIdx.x * 8;
    const int t    = threadIdx.x;

    __shared__ float s_rows[8][128];
    __shared__ float a_rows[8][16];
    __shared__ float p_rows[8][16];
    __shared__ float tail[16][128];

    {
        const float4* src = (const float4*)(states + row0 * 128);
        float4* dst = (float4*)&s_rows[0][0];
        dst[t]       = src[t];
        dst[t + 128] = src[t + 128];
        const int r = t >> 4, d = t & 15;
        a_rows[r][d] = actions[(row0 + r) * 16 + d];
        p_rows[r][d] = policies[(row0 + r) * 16 + d];
        const float4* tsrc = (const float4*)(W_sape + 128 * 128);
        float4* tdst = (float4*)&tail[0][0];
        #pragma unroll
        for (int k = 0; k < 4; k++) tdst[t + k * 128] = tsrc[t + k * 128];
    }
    __syncthreads();

    float acc_se[8] = {0,0,0,0,0,0,0,0};
    float acc_sp[8] = {0,0,0,0,0,0,0,0};
    #pragma unroll 2
    for (int dc = 0; dc < 32; dc++) {
        float wse[4], wsp[4];
        #pragma unroll
        for (int j = 0; j < 4; j++) {
            wse[j] = W_se[(dc * 4 + j) * 128 + t];
            wsp[j] = W_sape[(dc * 4 + j) * 128 + t];
        }
        #pragma unroll
        for (int r = 0; r < 8; r++) {
            const float4 s4 = *(const float4*)&s_rows[r][dc * 4];
            acc_se[r] += s4.x * wse[0] + s4.y * wse[1] + s4.z * wse[2] + s4.w * wse[3];
            acc_sp[r] += s4.x * wsp[0] + s4.y * wsp[1] + s4.z * wsp[2] + s4.w * wsp[3];
        }
    }
    const float bse = b_se[t], bsp = b_sape[t];
    #pragma unroll
    for (int r = 0; r < 8; r++) {
        float aa = bsp + acc_sp[r];
        float pp = aa;
        #pragma unroll
        for (int d = 0; d < 16; d++) {
            const float wv = tail[d][t];
            aa += a_rows[r][d] * wv;
            pp += p_rows[r][d] * wv;
        }
        se[(row0 + r) * 128 + t] = leaky(bse + acc_se[r]);
        xa[(row0 + r) * 128 + t] = leaky(aa);
        xp[(row0 + r) * 128 + t] = leaky(pp);
    }
}

// ---------------------------------------------------------------------------
// Kernel B: 1024 threads, 5 barriers, 70,656B LDS (2 blocks/CU = 32 waves).
// Wave split: waves 0-7 -> q,k; waves 8-15 -> ava,avp (each reads only its
// own weight matrices, so per-block weight traffic is unchanged).
// ---------------------------------------------------------------------------
#define RS 68

__global__ __launch_bounds__(1024, 2) void kB(
    const float* __restrict__ se, const float* __restrict__ xa,
    const float* __restrict__ xp, const float* __restrict__ wT,
    const float* __restrict__ W_f1, const float* __restrict__ ln_g,
    float* __restrict__ w_out,
    float* __restrict__ SG, float* __restrict__ DG,
    float* __restrict__ sumS, float* __restrict__ sumS2,
    float* __restrict__ sumD, float* __restrict__ sumD2,
    float* __restrict__ dotSD, float* __restrict__ GW)
{
    const int bh   = blockIdx.x;
    const int b    = bh >> 2;
    const int h    = bh & 3;
    const int t    = threadIdx.x;
    const int wave = t >> 6;
    const int e    = t & 63;

    __shared__ float bufSE[N * 128];  // se -> Wg[e*64+c]
    __shared__ float bufXA[N * 128];  // xa; [0,2048) becomes ava[i*64+e]
    __shared__ float bufXP[N * 128];  // xp; becomes diff[i*RS+e]
    __shared__ float q_s[N * RS];     // q -> S
    __shared__ float k_s[N * RS];     // k
    __shared__ float sc[N * 32];      // scores -> w

    // ---- stage 0: stage all three row blocks
    ((float4*)bufSE)[t] = ((const float4*)(se + b * N * 128))[t];
    ((float4*)bufXA)[t] = ((const float4*)(xa + b * N * 128))[t];
    ((float4*)bufXP)[t] = ((const float4*)(xp + b * N * 128))[t];
    __syncthreads();

    const float4* WqT = (const float4*)(wT + (h * 3 + 0) * 8192);
    const float4* WkT = (const float4*)(wT + (h * 3 + 1) * 8192);
    const float4* WvT = (const float4*)(wT + (h * 3 + 2) * 8192);

    // ---- stage 1: wave-split GEMMs, 4 rows per thread
    float av[4] = {0,0,0,0}, ap[4] = {0,0,0,0};
    if (wave < 8) {
        const int i0 = wave * 4;
        float aq[4] = {0,0,0,0}, ak[4] = {0,0,0,0};
        #pragma unroll 2
        for (int dc = 0; dc < 32; dc++) {
            const float4 wq = WqT[dc * 64 + e];
            const float4 wk = WkT[dc * 64 + e];
            #pragma unroll
            for (int r = 0; r < 4; r++) {
                const float4 s4 = *(const float4*)&bufSE[(i0 + r) * 128 + dc * 4];
                aq[r] += s4.x * wq.x + s4.y * wq.y + s4.z * wq.z + s4.w * wq.w;
                ak[r] += s4.x * wk.x + s4.y * wk.y + s4.z * wk.z + s4.w * wk.w;
            }
        }
        #pragma unroll
        for (int r = 0; r < 4; r++) {
            q_s[(i0 + r) * RS + e] = aq[r];
            k_s[(i0 + r) * RS + e] = ak[r];
        }
    } else {
        const int i0 = (wave - 8) * 4;
        #pragma unroll 2
        for (int dc = 0; dc < 32; dc++) {
            const float4 wv = WvT[dc * 64 + e];
            #pragma unroll
            for (int r = 0; r < 4; r++) {
                const float4 a4 = *(const float4*)&bufXA[(i0 + r) * 128 + dc * 4];
                const float4 p4 = *(const float4*)&bufXP[(i0 + r) * 128 + dc * 4];
                av[r] += a4.x * wv.x + a4.y * wv.y + a4.z * wv.z + a4.w * wv.w;
                ap[r] += p4.x * wv.x + p4.y * wv.y + p4.z * wv.z + p4.w * wv.w;
            }
        }
    }
    __syncthreads();

    // ---- stage 2: ava/diff from regs; Wg staging; scores
    if (wave >= 8) {
        const int i0 = (wave - 8) * 4;
        #pragma unroll
        for (int r = 0; r < 4; r++) {
            bufXA[(i0 + r) * 64 + e] = av[r];
            bufXP[(i0 + r) * RS + e] = ap[r] - av[r];   // diff
        }
    }
    {   // Wg = ln_g (.) W_f1h -> bufSE (se dead)
        const float4 f4 = ((const float4*)(W_f1 + h * 64 * 64))[t];
        const float g = ln_g[h * 64 + (t >> 4)];
        float4 wg; wg.x = g * f4.x; wg.y = g * f4.y; wg.z = g * f4.z; wg.w = g * f4.w;
        ((float4*)bufSE)[t] = wg;
    }
    {   // scores: one (i,j) per thread
        const int i = t >> 5, j = t & 31;
        float a = 0.f;
        #pragma unroll
        for (int e4 = 0; e4 < 16; e4++) {
            const float4 qv = *(const float4*)&q_s[i * RS + e4 * 4];
            const float4 kv = *(const float4*)&k_s[j * RS + e4 * 4];
            a += qv.x * kv.x + qv.y * kv.y + qv.z * kv.z + qv.w * kv.w;
        }
        sc[i * 32 + j] = a * 0.125f;
    }
    __syncthreads();

    // ---- stage 3: softmax (waves 0-7) | DG (waves 8-15); then GW, sumD
    if (t < 512) {
        const int i = t >> 4, l = t & 15;
        float v0 = sc[i * 32 + l], v1 = sc[i * 32 + 16 + l];
        float mx = fmaxf(v0, v1);
        #pragma unroll
        for (int m = 8; m; m >>= 1) mx = fmaxf(mx, __shfl_xor(mx, m));
        float e0 = __expf(v0 - mx), e1 = __expf(v1 - mx);
        float sum = e0 + e1;
        #pragma unroll
        for (int m = 8; m; m >>= 1) sum += __shfl_xor(sum, m);
        const float inv = 1.f / sum;
        e0 *= inv; e1 *= inv;
        sc[i * 32 + l]      = e0;
        sc[i * 32 + 16 + l] = e1;
        w_out[(bh * N + i) * N + l]      = e0;
        w_out[(bh * N + i) * N + 16 + l] = e1;
        if (t < 64) {           // GW column sums of Wg
            float g = 0.f;
            #pragma unroll 8
            for (int ee = 0; ee < 64; ee++) g += bufSE[ee * 64 + t];
            GW[h * 64 + t] = g;
        } else if (t < 96) {    // sumD/sumD2 from diff
            const int r = t - 64;
            float s1 = 0.f, s2 = 0.f;
            #pragma unroll
            for (int e4 = 0; e4 < 16; e4++) {
                const float4 v = *(const float4*)&bufXP[r * RS + e4 * 4];
                s1 += v.x + v.y + v.z + v.w;
                s2 += v.x * v.x + v.y * v.y + v.z * v.z + v.w * v.w;
            }
            sumD[bh * N + r] = s1; sumD2[bh * N + r] = s2;
        }
    } else {
        // DG = diff @ Wg : one float4-quad per thread
        const int idx = t - 512;
        const int r   = idx >> 4;
        const int c4  = (idx & 15) << 2;
        float4 acc = {0.f, 0.f, 0.f, 0.f};
        #pragma unroll 8
        for (int ee = 0; ee < 64; ee++) {
            const float s = bufXP[r * RS + ee];
            const float4 wv = *(const float4*)&bufSE[ee * 64 + c4];
            acc.x += s * wv.x; acc.y += s * wv.y;
            acc.z += s * wv.z; acc.w += s * wv.w;
        }
        *(float4*)&DG[(bh * N + r) * 64 + c4] = acc;
    }
    __syncthreads();

    // ---- stage 4: S = w @ ava  (2 rows per thread, into q_s)
    {
        const int i0 = wave * 2;
        float sa0 = 0.f, sa1 = 0.f;
        #pragma unroll
        for (int kc = 0; kc < 8; kc++) {
            const float4 s0 = *(const float4*)&sc[(i0 + 0) * 32 + kc * 4];
            const float4 s1 = *(const float4*)&sc[(i0 + 1) * 32 + kc * 4];
            const float a0 = bufXA[(kc * 4 + 0) * 64 + e];
            const float a1 = bufXA[(kc * 4 + 1) * 64 + e];
            const float a2 = bufXA[(kc * 4 + 2) * 64 + e];
            const float a3 = bufXA[(kc * 4 + 3) * 64 + e];
            sa0 += s0.x * a0 + s0.y * a1 + s0.z * a2 + s0.w * a3;
            sa1 += s1.x * a0 + s1.y * a1 + s1.z * a2 + s1.w * a3;
        }
        q_s[(i0 + 0) * RS + e] = sa0;
        q_s[(i0 + 1) * RS + e] = sa1;
    }
    __syncthreads();

    // ---- stage 5: dotSD (all) ; sumS/sumS2 (t<32) ; SG (t>=512)
    {
        const int i = t >> 5, j = t & 31;
        float a = 0.f;
        #pragma unroll
        for (int e4 = 0; e4 < 16; e4++) {
            const float4 sv = *(const float4*)&q_s[i * RS + e4 * 4];
            const float4 dv = *(const float4*)&bufXP[j * RS + e4 * 4];
            a += sv.x * dv.x + sv.y * dv.y + sv.z * dv.z + sv.w * dv.w;
        }
        dotSD[(bh * N + i) * N + j] = a;
    }
    if (t < 32) {
        const int r = t;
        float s1 = 0.f, s2 = 0.f;
        #pragma unroll
        for (int e4 = 0; e4 < 16; e4++) {
            const float4 v = *(const float4*)&q_s[r * RS + e4 * 4];
            s1 += v.x + v.y + v.z + v.w;
            s2 += v.x * v.x + v.y * v.y + v.z * v.z + v.w * v.w;
        }
        sumS[bh * N + r] = s1; sumS2[bh * N + r] = s2;
    } else if (t >= 512) {
        const int idx = t - 512;
        const int r   = idx >> 4;
        const int c4  = (idx & 15) << 2;
        float4 acc = {0.f, 0.f, 0.f, 0.f};
        #pragma unroll 8
        for (int ee = 0; ee < 64; ee++) {
            const float s = q_s[r * RS + ee];
            const float4 wv = *(const float4*)&bufSE[ee * 64 + c4];
            acc.x += s * wv.x; acc.y += s * wv.y;
            acc.z += s * wv.z; acc.w += s * wv.w;
        }
        *(float4*)&SG[(bh * N + r) * 64 + c4] = acc;
    }
}

// ---------------------------------------------------------------------------
// Kernel C (512 blocks: b x 4 i-groups of 8; 256 threads)
// ---------------------------------------------------------------------------
__global__ __launch_bounds__(256) void kC(
    const float* __restrict__ SG, const float* __restrict__ DG,
    const float* __restrict__ sumS, const float* __restrict__ sumS2,
    const float* __restrict__ sumD, const float* __restrict__ sumD2,
    const float* __restrict__ dotSD, const float* __restrict__ w_all,
    const float* __restrict__ GW, const float* __restrict__ ln_b,
    const float* __restrict__ W_f1, const float* __restrict__ W_f2,
    float* __restrict__ value)
{
    const int blk = blockIdx.x;
    const int b   = blk >> 2;
    const int i0  = (blk & 3) * 8;
    const int t   = threadIdx.x;

    __shared__ float SGs[8][256];
    __shared__ float GWs[256];
    __shared__ float BWs[64], wf2s[64];
    __shared__ float bwp[4][64];
    __shared__ float w_s[4][8][32];
    __shared__ float mu_s[4][8][32];
    __shared__ float inv_s[4][8][32];

    {
        const int c = t & 63, qq = t >> 6;
        float bacc = 0.f;
        #pragma unroll 4
        for (int r = 0; r < 64; r++)
            bacc += ln_b[qq * 64 + r] * W_f1[(qq * 64 + r) * 64 + c];
        bwp[qq][c] = bacc;
    }

    GWs[t] = GW[t];
    if (t < 64) wf2s[t] = W_f2[t];
    for (int idx4 = t; idx4 < 512; idx4 += 256) {
        const int ii  = idx4 >> 6;
        const int hc4 = idx4 & 63;
        const int hh  = hc4 >> 4, c4 = (hc4 & 15) * 4;
        ((float4*)&SGs[ii][0])[hc4] =
            *(const float4*)&SG[((b * 4 + hh) * 32 + i0 + ii) * 64 + c4];
    }
    for (int idx = t; idx < 1024; idx += 256) {
        const int hh = idx >> 8, ii = (idx >> 5) & 7, j = idx & 31;
        const int hi = (b * 4 + hh) * 32 + (i0 + ii);
        const int hj = (b * 4 + hh) * 32 + j;
        const float wv  = w_all[hi * 32 + j];
        const float dsd = dotSD[hi * 32 + j];
        const float mu  = (sumS[hi] + wv * sumD[hj]) * (1.f / 64.f);
        const float e2  = (sumS2[hi] + 2.f * wv * dsd + wv * wv * sumD2[hj]) * (1.f / 64.f);
        const float var = fmaxf(e2 - mu * mu, 0.f);
        w_s[hh][ii][j]   = wv;
        mu_s[hh][ii][j]  = mu;
        inv_s[hh][ii][j] = rsqrtf(var + LN_EPS);
    }
    __syncthreads();
    if (t < 64) BWs[t] = bwp[0][t] + bwp[1][t] + bwp[2][t] + bwp[3][t];
    __syncthreads();

    const int w0 = t >> 6;
    const int e  = t & 63;
    const float GW0 = GWs[e],       GW1 = GWs[64 + e];
    const float GW2 = GWs[128 + e], GW3 = GWs[192 + e];
    const float bwr = BWs[e], f2 = wf2s[e];
    const float* DGb = DG + b * H * N * 64;

    for (int jb = 0; jb < 8; jb++) {
        const int j = jb * 4 + w0;
        const float d0 = DGb[(0 * 32 + j) * 64 + e];
        const float d1 = DGb[(1 * 32 + j) * 64 + e];
        const float d2 = DGb[(2 * 32 + j) * 64 + e];
        const float d3 = DGb[(3 * 32 + j) * 64 + e];
        #pragma unroll
        for (int ii = 0; ii < 8; ii++) {
            float z = bwr;
            z += inv_s[0][ii][j] * (SGs[ii][e]       + w_s[0][ii][j] * d0 - mu_s[0][ii][j] * GW0);
            z += inv_s[1][ii][j] * (SGs[ii][64 + e]  + w_s[1][ii][j] * d1 - mu_s[1][ii][j] * GW1);
            z += inv_s[2][ii][j] * (SGs[ii][128 + e] + w_s[2][ii][j] * d2 - mu_s[2][ii][j] * GW2);
            z += inv_s[3][ii][j] * (SGs[ii][192 + e] + w_s[3][ii][j] * d3 - mu_s[3][ii][j] * GW3);
            float p = leaky(z) * f2;
            #pragma unroll
            for (int m = 32; m; m >>= 1) p += __shfl_xor(p, m);
            if (e == 0) value[(b * 32 + i0 + ii) * 32 + j] = p;
        }
    }
}

extern "C" void kernel_launch(void* const* d_in, const int* in_sizes, int n_in,
                              void* d_out, int out_size, void* d_ws, size_t ws_size,
                              hipStream_t stream)
{
    const float* states   = (const float*)d_in[0];
    const float* policies = (const float*)d_in[1];
    const float* actions  = (const float*)d_in[2];
    const float* W_se     = (const float*)d_in[3];
    const float* b_se     = (const float*)d_in[4];
    const float* W_sape   = (const float*)d_in[5];
    const float* b_sape   = (const float*)d_in[6];
    const float* Wk       = (const float*)d_in[7];
    const float* Wq       = (const float*)d_in[8];
    const float* Wv       = (const float*)d_in[9];
    const float* ln_g     = (const float*)d_in[10];
    const float* ln_b     = (const float*)d_in[11];
    const float* W_f1     = (const float*)d_in[12];
    const float* W_f2     = (const float*)d_in[13];

    float* out_value = (float*)d_out;
    float* out_w     = out_value + B * N * N;

    float* ws    = (float*)d_ws;
    float* se    = ws;
    float* xa    = se    + B * N * 128;
    float* xp    = xa    + B * N * 128;
    float* SG    = xp    + B * N * 128;
    float* DG    = SG    + B * H * N * 64;
    float* sumS  = DG    + B * H * N * 64;
    float* sumS2 = sumS  + B * H * N;
    float* sumD  = sumS2 + B * H * N;
    float* sumD2 = sumD  + B * H * N;
    float* dotSD = sumD2 + B * H * N;
    float* GW    = dotSD + B * H * N * N;
    float* wT    = GW    + 256;

    kT<<<12, 256, 0, stream>>>(Wk, Wq, Wv, wT);
    kA<<<512, 128, 0, stream>>>(states, policies, actions, W_se, b_se,
                                W_sape, b_sape, se, xa, xp);
    kB<<<B * H, 1024, 0, stream>>>(se, xa, xp, wT, W_f1, ln_g, out_w,
                                   SG, DG, sumS, sumS2, sumD, sumD2, dotSD, GW);
    kC<<<512, 256, 0, stream>>>(SG, DG, sumS, sumS2, sumD, sumD2, dotSD,
                                out_w, GW, ln_b, W_f1, W_f2, out_value);
}

// Round 7
// 163.641 us; speedup vs baseline: 1.2033x; 1.1423x over previous
//
#include <hip/hip_runtime.h>
#include <hip/hip_bf16.h>

#define B 128
#define N 32
#define DO 128
#define NA 16
#define H 4
#define DK 64
#define DV 64
#define LN_EPS 1e-5f
#define NEG_SLOPE 0.01f

typedef unsigned short u16;
typedef __attribute__((ext_vector_type(8))) short bf16x8;
typedef __attribute__((ext_vector_type(4))) float f32x4;

__device__ __forceinline__ float leaky(float x) {
    return x >= 0.f ? x : NEG_SLOPE * x;
}

__device__ __forceinline__ u16 f2bf(float x) {
    union { float f; unsigned int u; } v; v.f = x;
    unsigned int r = (v.u + 0x7FFF + ((v.u >> 16) & 1)) >> 16;
    return (u16)r;
}

// ---------------------------------------------------------------------------
// Kernel A: blocks 0..511: se/xa/xp (bf16 out), 8 rows per block.
//           blocks 512..515: repack Wq/Wk/Wv head (blk-512) -> bf16 wTb[n][k]
// ---------------------------------------------------------------------------
__global__ __launch_bounds__(128) void kA(
    const float* __restrict__ states, const float* __restrict__ policies,
    const float* __restrict__ actions, const float* __restrict__ W_se,
    const float* __restrict__ b_se, const float* __restrict__ W_sape,
    const float* __restrict__ b_sape,
    const float* __restrict__ Wk, const float* __restrict__ Wq,
    const float* __restrict__ Wv,
    u16* __restrict__ seb, u16* __restrict__ xab, u16* __restrict__ xpb,
    u16* __restrict__ wTb)
{
    const int t = threadIdx.x;

    __shared__ float s_rows[8][128];
    __shared__ float a_rows[8][16];
    __shared__ float p_rows[8][16];
    __shared__ float tail[16][128];
    __shared__ float wls[8192];       // transpose staging (blocks >= 512)

    if (blockIdx.x >= 512) {
        const int hh = blockIdx.x - 512;
        for (int m = 0; m < 3; m++) {
            const float* src = (m == 0 ? Wq : (m == 1 ? Wk : Wv)) + hh * 8192;
            for (int idx = t; idx < 2048; idx += 128)
                ((float4*)wls)[idx] = ((const float4*)src)[idx];
            __syncthreads();
            u16* dst = wTb + (hh * 3 + m) * 8192;
            for (int idx = t; idx < 8192; idx += 128) {
                const int n = idx >> 7, k = idx & 127;
                dst[idx] = f2bf(wls[k * 64 + n]);
            }
            __syncthreads();
        }
        return;
    }

    const int row0 = blockIdx.x * 8;
    {
        const float4* src = (const float4*)(states + row0 * 128);
        float4* dst = (float4*)&s_rows[0][0];
        dst[t]       = src[t];
        dst[t + 128] = src[t + 128];
        const int r = t >> 4, d = t & 15;
        a_rows[r][d] = actions[(row0 + r) * 16 + d];
        p_rows[r][d] = policies[(row0 + r) * 16 + d];
        const float4* tsrc = (const float4*)(W_sape + 128 * 128);
        float4* tdst = (float4*)&tail[0][0];
        #pragma unroll
        for (int k = 0; k < 4; k++) tdst[t + k * 128] = tsrc[t + k * 128];
    }
    __syncthreads();

    float acc_se[8] = {0,0,0,0,0,0,0,0};
    float acc_sp[8] = {0,0,0,0,0,0,0,0};
    #pragma unroll 2
    for (int dc = 0; dc < 32; dc++) {
        float wse[4], wsp[4];
        #pragma unroll
        for (int j = 0; j < 4; j++) {
            wse[j] = W_se[(dc * 4 + j) * 128 + t];
            wsp[j] = W_sape[(dc * 4 + j) * 128 + t];
        }
        #pragma unroll
        for (int r = 0; r < 8; r++) {
            const float4 s4 = *(const float4*)&s_rows[r][dc * 4];
            acc_se[r] += s4.x * wse[0] + s4.y * wse[1] + s4.z * wse[2] + s4.w * wse[3];
            acc_sp[r] += s4.x * wsp[0] + s4.y * wsp[1] + s4.z * wsp[2] + s4.w * wsp[3];
        }
    }
    const float bse = b_se[t], bsp = b_sape[t];
    #pragma unroll
    for (int r = 0; r < 8; r++) {
        float aa = bsp + acc_sp[r];
        float pp = aa;
        #pragma unroll
        for (int d = 0; d < 16; d++) {
            const float wv = tail[d][t];
            aa += a_rows[r][d] * wv;
            pp += p_rows[r][d] * wv;
        }
        seb[(row0 + r) * 128 + t] = f2bf(leaky(bse + acc_se[r]));
        xab[(row0 + r) * 128 + t] = f2bf(leaky(aa));
        xpb[(row0 + r) * 128 + t] = f2bf(leaky(pp));
    }
}

// ---------------------------------------------------------------------------
// Kernel B: 1024 threads; stage-1 GEMMs via bf16 MFMA (16x16x32).
// Wave w owns tiles tau=2w,2w+1: mat=tau>>3 (0=q,1=k,2=ava,3=avp),
// mt=(tau>>2)&1 (row half), nt=tau&3 (col quarter). avp accs held in regs.
// LDS 79,360B -> 2 blocks/CU.
// ---------------------------------------------------------------------------
#define RS 68

__global__ __launch_bounds__(1024, 2) void kB(
    const u16* __restrict__ seb, const u16* __restrict__ xab,
    const u16* __restrict__ xpb, const u16* __restrict__ wTb,
    const float* __restrict__ W_f1, const float* __restrict__ ln_g,
    float* __restrict__ w_out,
    float* __restrict__ SG, float* __restrict__ DG,
    float* __restrict__ sumS, float* __restrict__ sumS2,
    float* __restrict__ sumD, float* __restrict__ sumD2,
    float* __restrict__ dotSD, float* __restrict__ GW)
{
    const int bh   = blockIdx.x;
    const int b    = bh >> 2;
    const int h    = bh & 3;
    const int t    = threadIdx.x;
    const int wave = t >> 6;
    const int e    = t & 63;

    __shared__ alignas(16) u16 sSE[32 * 128];   // 8KB bf16
    __shared__ alignas(16) u16 sXA[32 * 128];   // 8KB
    __shared__ alignas(16) u16 sXP[32 * 128];   // 8KB
    __shared__ alignas(16) float q_s[32 * RS];  // q -> S
    __shared__ alignas(16) float k_s[32 * RS];  // k
    __shared__ alignas(16) float avaB[32 * 64]; // ava fp32
    __shared__ alignas(16) float diffs[32 * RS];// diff fp32
    __shared__ alignas(16) float sc[32 * 32];   // scores -> w
    __shared__ alignas(16) float wg[64 * 64];   // Wg = g (.) W_f1h

    // ---- stage 0: stage bf16 inputs + Wg
    if (t < 512) ((uint4*)sSE)[t] = ((const uint4*)(seb + b * 4096))[t];
    else         ((uint4*)sXA)[t - 512] = ((const uint4*)(xab + b * 4096))[t - 512];
    if (t < 512) ((uint4*)sXP)[t] = ((const uint4*)(xpb + b * 4096))[t];
    {
        const float4 f4 = ((const float4*)(W_f1 + h * 4096))[t];
        const float g = ln_g[h * 64 + (t >> 4)];
        float4 w4; w4.x = g * f4.x; w4.y = g * f4.y; w4.z = g * f4.z; w4.w = g * f4.w;
        ((float4*)wg)[t] = w4;
    }
    __syncthreads();

    // ---- stage 1: MFMA, 2 tiles per wave
    f32x4 acc[2];
    #pragma unroll
    for (int p = 0; p < 2; p++) {
        const int tau = wave * 2 + p;
        const int mat = tau >> 3;
        const int mt  = (tau >> 2) & 1, nt = tau & 3;
        const u16* X  = (mat <= 1) ? sSE : (mat == 2 ? sXA : sXP);
        const int widx = (mat == 0) ? 0 : (mat == 1 ? 1 : 2);
        const int row  = mt * 16 + (e & 15);
        const int n    = nt * 16 + (e & 15);
        const int kb   = (e >> 4) * 8;
        const u16* wsrc = wTb + ((h * 3 + widx) * 64 + n) * 128;
        f32x4 a = {0.f, 0.f, 0.f, 0.f};
        #pragma unroll
        for (int ks = 0; ks < 4; ks++) {
            const bf16x8 af = *(const bf16x8*)&X[row * 128 + ks * 32 + kb];
            const bf16x8 bf = *(const bf16x8*)&wsrc[ks * 32 + kb];
            a = __builtin_amdgcn_mfma_f32_16x16x32_bf16(af, bf, a, 0, 0, 0);
        }
        acc[p] = a;
    }
    #pragma unroll
    for (int p = 0; p < 2; p++) {
        const int tau = wave * 2 + p;
        const int mat = tau >> 3;
        const int mt  = (tau >> 2) & 1, nt = tau & 3;
        const int c   = nt * 16 + (e & 15);
        const int r0  = mt * 16 + (e >> 4) * 4;
        if (mat == 0) {
            #pragma unroll
            for (int v = 0; v < 4; v++) q_s[(r0 + v) * RS + c] = acc[p][v];
        } else if (mat == 1) {
            #pragma unroll
            for (int v = 0; v < 4; v++) k_s[(r0 + v) * RS + c] = acc[p][v];
        } else if (mat == 2) {
            #pragma unroll
            for (int v = 0; v < 4; v++) avaB[(r0 + v) * 64 + c] = acc[p][v];
        } // mat==3: held in regs
    }
    __syncthreads();

    // ---- stage 2: scores (1/thread); avp waves write diff; GW (t<64)
    {
        const int i = t >> 5, j = t & 31;
        float a = 0.f;
        #pragma unroll
        for (int e4 = 0; e4 < 16; e4++) {
            const float4 qv = *(const float4*)&q_s[i * RS + e4 * 4];
            const float4 kv = *(const float4*)&k_s[j * RS + e4 * 4];
            a += qv.x * kv.x + qv.y * kv.y + qv.z * kv.z + qv.w * kv.w;
        }
        sc[i * 32 + j] = a * 0.125f;
    }
    if (wave >= 12) {
        #pragma unroll
        for (int p = 0; p < 2; p++) {
            const int tau = wave * 2 + p;
            const int mt  = (tau >> 2) & 1, nt = tau & 3;
            const int c   = nt * 16 + (e & 15);
            const int r0  = mt * 16 + (e >> 4) * 4;
            #pragma unroll
            for (int v = 0; v < 4; v++)
                diffs[(r0 + v) * RS + c] = acc[p][v] - avaB[(r0 + v) * 64 + c];
        }
    }
    if (t < 64) {
        float g = 0.f;
        #pragma unroll 8
        for (int ee = 0; ee < 64; ee++) g += wg[ee * 64 + t];
        GW[h * 64 + t] = g;
    }
    __syncthreads();

    // ---- stage 3: softmax (t<512, +sumD on t<32) | DG (t>=512)
    if (t < 512) {
        const int i = t >> 4, l = t & 15;
        float v0 = sc[i * 32 + l], v1 = sc[i * 32 + 16 + l];
        float mx = fmaxf(v0, v1);
        #pragma unroll
        for (int m = 8; m; m >>= 1) mx = fmaxf(mx, __shfl_xor(mx, m));
        float e0 = __expf(v0 - mx), e1 = __expf(v1 - mx);
        float sum = e0 + e1;
        #pragma unroll
        for (int m = 8; m; m >>= 1) sum += __shfl_xor(sum, m);
        const float inv = 1.f / sum;
        e0 *= inv; e1 *= inv;
        sc[i * 32 + l]      = e0;
        sc[i * 32 + 16 + l] = e1;
        w_out[(bh * N + i) * N + l]      = e0;
        w_out[(bh * N + i) * N + 16 + l] = e1;
        if (t < 32) {
            const int r = t;
            float s1 = 0.f, s2 = 0.f;
            #pragma unroll
            for (int e4 = 0; e4 < 16; e4++) {
                const float4 v = *(const float4*)&diffs[r * RS + e4 * 4];
                s1 += v.x + v.y + v.z + v.w;
                s2 += v.x * v.x + v.y * v.y + v.z * v.z + v.w * v.w;
            }
            sumD[bh * N + r] = s1; sumD2[bh * N + r] = s2;
        }
    } else {
        const int idx = t - 512;
        const int r   = idx >> 4;
        const int c4  = (idx & 15) << 2;
        float4 a4 = {0.f, 0.f, 0.f, 0.f};
        #pragma unroll 8
        for (int ee = 0; ee < 64; ee++) {
            const float s = diffs[r * RS + ee];
            const float4 wv = *(const float4*)&wg[ee * 64 + c4];
            a4.x += s * wv.x; a4.y += s * wv.y;
            a4.z += s * wv.z; a4.w += s * wv.w;
        }
        *(float4*)&DG[(bh * N + r) * 64 + c4] = a4;
    }
    __syncthreads();

    // ---- stage 4: S = w @ ava (2 rows/thread)
    {
        const int i0 = wave * 2;
        float sa0 = 0.f, sa1 = 0.f;
        #pragma unroll
        for (int kc = 0; kc < 8; kc++) {
            const float4 s0 = *(const float4*)&sc[(i0 + 0) * 32 + kc * 4];
            const float4 s1 = *(const float4*)&sc[(i0 + 1) * 32 + kc * 4];
            const float a0 = avaB[(kc * 4 + 0) * 64 + e];
            const float a1 = avaB[(kc * 4 + 1) * 64 + e];
            const float a2 = avaB[(kc * 4 + 2) * 64 + e];
            const float a3 = avaB[(kc * 4 + 3) * 64 + e];
            sa0 += s0.x * a0 + s0.y * a1 + s0.z * a2 + s0.w * a3;
            sa1 += s1.x * a0 + s1.y * a1 + s1.z * a2 + s1.w * a3;
        }
        q_s[(i0 + 0) * RS + e] = sa0;
        q_s[(i0 + 1) * RS + e] = sa1;
    }
    __syncthreads();

    // ---- stage 5: dotSD (all); sumS (t<32); SG (t>=512)
    {
        const int i = t >> 5, j = t & 31;
        float a = 0.f;
        #pragma unroll
        for (int e4 = 0; e4 < 16; e4++) {
            const float4 sv = *(const float4*)&q_s[i * RS + e4 * 4];
            const float4 dv = *(const float4*)&diffs[j * RS + e4 * 4];
            a += sv.x * dv.x + sv.y * dv.y + sv.z * dv.z + sv.w * dv.w;
        }
        dotSD[(bh * N + i) * N + j] = a;
    }
    if (t < 32) {
        const int r = t;
        float s1 = 0.f, s2 = 0.f;
        #pragma unroll
        for (int e4 = 0; e4 < 16; e4++) {
            const float4 v = *(const float4*)&q_s[r * RS + e4 * 4];
            s1 += v.x + v.y + v.z + v.w;
            s2 += v.x * v.x + v.y * v.y + v.z * v.z + v.w * v.w;
        }
        sumS[bh * N + r] = s1; sumS2[bh * N + r] = s2;
    } else if (t >= 512) {
        const int idx = t - 512;
        const int r   = idx >> 4;
        const int c4  = (idx & 15) << 2;
        float4 a4 = {0.f, 0.f, 0.f, 0.f};
        #pragma unroll 8
        for (int ee = 0; ee < 64; ee++) {
            const float s = q_s[r * RS + ee];
            const float4 wv = *(const float4*)&wg[ee * 64 + c4];
            a4.x += s * wv.x; a4.y += s * wv.y;
            a4.z += s * wv.z; a4.w += s * wv.w;
        }
        *(float4*)&SG[(bh * N + r) * 64 + c4] = a4;
    }
}

// ---------------------------------------------------------------------------
// Kernel C (512 blocks: b x 4 i-groups of 8; 256 threads) — unchanged
// ---------------------------------------------------------------------------
__global__ __launch_bounds__(256) void kC(
    const float* __restrict__ SG, const float* __restrict__ DG,
    const float* __restrict__ sumS, const float* __restrict__ sumS2,
    const float* __restrict__ sumD, const float* __restrict__ sumD2,
    const float* __restrict__ dotSD, const float* __restrict__ w_all,
    const float* __restrict__ GW, const float* __restrict__ ln_b,
    const float* __restrict__ W_f1, const float* __restrict__ W_f2,
    float* __restrict__ value)
{
    const int blk = blockIdx.x;
    const int b   = blk >> 2;
    const int i0  = (blk & 3) * 8;
    const int t   = threadIdx.x;

    __shared__ float SGs[8][256];
    __shared__ float GWs[256];
    __shared__ float BWs[64], wf2s[64];
    __shared__ float bwp[4][64];
    __shared__ float w_s[4][8][32];
    __shared__ float mu_s[4][8][32];
    __shared__ float inv_s[4][8][32];

    {
        const int c = t & 63, qq = t >> 6;
        float bacc = 0.f;
        #pragma unroll 4
        for (int r = 0; r < 64; r++)
            bacc += ln_b[qq * 64 + r] * W_f1[(qq * 64 + r) * 64 + c];
        bwp[qq][c] = bacc;
    }

    GWs[t] = GW[t];
    if (t < 64) wf2s[t] = W_f2[t];
    for (int idx4 = t; idx4 < 512; idx4 += 256) {
        const int ii  = idx4 >> 6;
        const int hc4 = idx4 & 63;
        const int hh  = hc4 >> 4, c4 = (hc4 & 15) * 4;
        ((float4*)&SGs[ii][0])[hc4] =
            *(const float4*)&SG[((b * 4 + hh) * 32 + i0 + ii) * 64 + c4];
    }
    for (int idx = t; idx < 1024; idx += 256) {
        const int hh = idx >> 8, ii = (idx >> 5) & 7, j = idx & 31;
        const int hi = (b * 4 + hh) * 32 + (i0 + ii);
        const int hj = (b * 4 + hh) * 32 + j;
        const float wv  = w_all[hi * 32 + j];
        const float dsd = dotSD[hi * 32 + j];
        const float mu  = (sumS[hi] + wv * sumD[hj]) * (1.f / 64.f);
        const float e2  = (sumS2[hi] + 2.f * wv * dsd + wv * wv * sumD2[hj]) * (1.f / 64.f);
        const float var = fmaxf(e2 - mu * mu, 0.f);
        w_s[hh][ii][j]   = wv;
        mu_s[hh][ii][j]  = mu;
        inv_s[hh][ii][j] = rsqrtf(var + LN_EPS);
    }
    __syncthreads();
    if (t < 64) BWs[t] = bwp[0][t] + bwp[1][t] + bwp[2][t] + bwp[3][t];
    __syncthreads();

    const int w0 = t >> 6;
    const int e  = t & 63;
    const float GW0 = GWs[e],       GW1 = GWs[64 + e];
    const float GW2 = GWs[128 + e], GW3 = GWs[192 + e];
    const float bwr = BWs[e], f2 = wf2s[e];
    const float* DGb = DG + b * H * N * 64;

    for (int jb = 0; jb < 8; jb++) {
        const int j = jb * 4 + w0;
        const float d0 = DGb[(0 * 32 + j) * 64 + e];
        const float d1 = DGb[(1 * 32 + j) * 64 + e];
        const float d2 = DGb[(2 * 32 + j) * 64 + e];
        const float d3 = DGb[(3 * 32 + j) * 64 + e];
        #pragma unroll
        for (int ii = 0; ii < 8; ii++) {
            float z = bwr;
            z += inv_s[0][ii][j] * (SGs[ii][e]       + w_s[0][ii][j] * d0 - mu_s[0][ii][j] * GW0);
            z += inv_s[1][ii][j] * (SGs[ii][64 + e]  + w_s[1][ii][j] * d1 - mu_s[1][ii][j] * GW1);
            z += inv_s[2][ii][j] * (SGs[ii][128 + e] + w_s[2][ii][j] * d2 - mu_s[2][ii][j] * GW2);
            z += inv_s[3][ii][j] * (SGs[ii][192 + e] + w_s[3][ii][j] * d3 - mu_s[3][ii][j] * GW3);
            float p = leaky(z) * f2;
            #pragma unroll
            for (int m = 32; m; m >>= 1) p += __shfl_xor(p, m);
            if (e == 0) value[(b * 32 + i0 + ii) * 32 + j] = p;
        }
    }
}

extern "C" void kernel_launch(void* const* d_in, const int* in_sizes, int n_in,
                              void* d_out, int out_size, void* d_ws, size_t ws_size,
                              hipStream_t stream)
{
    const float* states   = (const float*)d_in[0];
    const float* policies = (const float*)d_in[1];
    const float* actions  = (const float*)d_in[2];
    const float* W_se     = (const float*)d_in[3];
    const float* b_se     = (const float*)d_in[4];
    const float* W_sape   = (const float*)d_in[5];
    const float* b_sape   = (const float*)d_in[6];
    const float* Wk       = (const float*)d_in[7];
    const float* Wq       = (const float*)d_in[8];
    const float* Wv       = (const float*)d_in[9];
    const float* ln_g     = (const float*)d_in[10];
    const float* ln_b     = (const float*)d_in[11];
    const float* W_f1     = (const float*)d_in[12];
    const float* W_f2     = (const float*)d_in[13];

    float* out_value = (float*)d_out;
    float* out_w     = out_value + B * N * N;

    float* ws    = (float*)d_ws;
    float* SG    = ws;                       // 1,048,576
    float* DG    = SG    + 1048576;          // 1,048,576
    float* sumS  = DG    + 1048576;          // 16,384
    float* sumS2 = sumS  + 16384;
    float* sumD  = sumS2 + 16384;
    float* sumD2 = sumD  + 16384;
    float* dotSD = sumD2 + 16384;            // 524,288
    float* GW    = dotSD + 524288;           // 256
    u16*   seb   = (u16*)(GW + 256);         // 524,288 u16
    u16*   xab   = seb + 524288;
    u16*   xpb   = xab + 524288;
    u16*   wTb   = xpb + 524288;             // 98,304 u16

    kA<<<516, 128, 0, stream>>>(states, policies, actions, W_se, b_se,
                                W_sape, b_sape, Wk, Wq, Wv,
                                seb, xab, xpb, wTb);
    kB<<<B * H, 1024, 0, stream>>>(seb, xab, xpb, wTb, W_f1, ln_g, out_w,
                                   SG, DG, sumS, sumS2, sumD, sumD2, dotSD, GW);
    kC<<<512, 256, 0, stream>>>(SG, DG, sumS, sumS2, sumD, sumD2, dotSD,
                                out_w, GW, ln_b, W_f1, W_f2, out_value);
}

// Round 8
// 154.303 us; speedup vs baseline: 1.2761x; 1.0605x over previous
//
#include <hip/hip_runtime.h>
#include <hip/hip_bf16.h>

#define B 128
#define N 32
#define DO 128
#define NA 16
#define H 4
#define DK 64
#define DV 64
#define LN_EPS 1e-5f
#define NEG_SLOPE 0.01f

typedef unsigned short u16;
typedef __attribute__((ext_vector_type(8))) short bf16x8;
typedef __attribute__((ext_vector_type(4))) float f32x4;

__device__ __forceinline__ float leaky(float x) {
    return x >= 0.f ? x : NEG_SLOPE * x;
}

__device__ __forceinline__ u16 f2bf(float x) {
    union { float f; unsigned int u; } v; v.f = x;
    unsigned int r = (v.u + 0x7FFF + ((v.u >> 16) & 1)) >> 16;
    return (u16)r;
}

__device__ __forceinline__ float bf2f(u16 x) {
    union { unsigned int u; float f; } v; v.u = ((unsigned int)x) << 16;
    return v.f;
}

// ---------------------------------------------------------------------------
// Kernel A: blocks 0..511: se/xa/xp (bf16 out), 8 rows per block.
//           blocks 512..515: repack Wq/Wk/Wv head (blk-512) -> bf16 wTb[n][k]
// ---------------------------------------------------------------------------
__global__ __launch_bounds__(128) void kA(
    const float* __restrict__ states, const float* __restrict__ policies,
    const float* __restrict__ actions, const float* __restrict__ W_se,
    const float* __restrict__ b_se, const float* __restrict__ W_sape,
    const float* __restrict__ b_sape,
    const float* __restrict__ Wk, const float* __restrict__ Wq,
    const float* __restrict__ Wv,
    u16* __restrict__ seb, u16* __restrict__ xab, u16* __restrict__ xpb,
    u16* __restrict__ wTb)
{
    const int t = threadIdx.x;

    __shared__ float s_rows[8][128];
    __shared__ float a_rows[8][16];
    __shared__ float p_rows[8][16];
    __shared__ float tail[16][128];
    __shared__ float wls[8192];

    if (blockIdx.x >= 512) {
        const int hh = blockIdx.x - 512;
        for (int m = 0; m < 3; m++) {
            const float* src = (m == 0 ? Wq : (m == 1 ? Wk : Wv)) + hh * 8192;
            for (int idx = t; idx < 2048; idx += 128)
                ((float4*)wls)[idx] = ((const float4*)src)[idx];
            __syncthreads();
            u16* dst = wTb + (hh * 3 + m) * 8192;
            for (int idx = t; idx < 8192; idx += 128) {
                const int n = idx >> 7, k = idx & 127;
                dst[idx] = f2bf(wls[k * 64 + n]);
            }
            __syncthreads();
        }
        return;
    }

    const int row0 = blockIdx.x * 8;
    {
        const float4* src = (const float4*)(states + row0 * 128);
        float4* dst = (float4*)&s_rows[0][0];
        dst[t]       = src[t];
        dst[t + 128] = src[t + 128];
        const int r = t >> 4, d = t & 15;
        a_rows[r][d] = actions[(row0 + r) * 16 + d];
        p_rows[r][d] = policies[(row0 + r) * 16 + d];
        const float4* tsrc = (const float4*)(W_sape + 128 * 128);
        float4* tdst = (float4*)&tail[0][0];
        #pragma unroll
        for (int k = 0; k < 4; k++) tdst[t + k * 128] = tsrc[t + k * 128];
    }
    __syncthreads();

    float acc_se[8] = {0,0,0,0,0,0,0,0};
    float acc_sp[8] = {0,0,0,0,0,0,0,0};
    #pragma unroll 2
    for (int dc = 0; dc < 32; dc++) {
        float wse[4], wsp[4];
        #pragma unroll
        for (int j = 0; j < 4; j++) {
            wse[j] = W_se[(dc * 4 + j) * 128 + t];
            wsp[j] = W_sape[(dc * 4 + j) * 128 + t];
        }
        #pragma unroll
        for (int r = 0; r < 8; r++) {
            const float4 s4 = *(const float4*)&s_rows[r][dc * 4];
            acc_se[r] += s4.x * wse[0] + s4.y * wse[1] + s4.z * wse[2] + s4.w * wse[3];
            acc_sp[r] += s4.x * wsp[0] + s4.y * wsp[1] + s4.z * wsp[2] + s4.w * wsp[3];
        }
    }
    const float bse = b_se[t], bsp = b_sape[t];
    #pragma unroll
    for (int r = 0; r < 8; r++) {
        float aa = bsp + acc_sp[r];
        float pp = aa;
        #pragma unroll
        for (int d = 0; d < 16; d++) {
            const float wv = tail[d][t];
            aa += a_rows[r][d] * wv;
            pp += p_rows[r][d] * wv;
        }
        seb[(row0 + r) * 128 + t] = f2bf(leaky(bse + acc_se[r]));
        xab[(row0 + r) * 128 + t] = f2bf(leaky(aa));
        xpb[(row0 + r) * 128 + t] = f2bf(leaky(pp));
    }
}

// ---------------------------------------------------------------------------
// Kernel B: 1024 threads, all matmuls via bf16 MFMA 16x16x32.
// Strides (bf16 units): staging 136, qb/kb/diffb/Sb/WgT 72, avaT/wb 40.
// Phases: 0 stage | A: M1 q,k,ava,avp | B: scores+softmax / diff / GW |
//         C: S=w@ava + sumD / DG | D: dotSD / SG / sumS.
// ---------------------------------------------------------------------------
__global__ __launch_bounds__(1024, 2) void kB(
    const u16* __restrict__ seb, const u16* __restrict__ xab,
    const u16* __restrict__ xpb, const u16* __restrict__ wTb,
    const float* __restrict__ W_f1, const float* __restrict__ ln_g,
    float* __restrict__ w_out,
    float* __restrict__ SG, float* __restrict__ DG,
    float* __restrict__ sumS, float* __restrict__ sumS2,
    float* __restrict__ sumD, float* __restrict__ sumD2,
    float* __restrict__ dotSD, float* __restrict__ GW)
{
    const int bh   = blockIdx.x;
    const int b    = bh >> 2;
    const int h    = bh & 3;
    const int t    = threadIdx.x;
    const int wave = t >> 6;
    const int e    = t & 63;
    const int q16  = e >> 4;   // quad
    const int l16  = e & 15;   // lane-in-16

    __shared__ alignas(16) u16   sSE[32 * 136];
    __shared__ alignas(16) u16   sXA[32 * 136];
    __shared__ alignas(16) u16   sXP[32 * 136];
    __shared__ alignas(16) u16   WgT[64 * 72];   // Wg^T[c][e]
    __shared__ alignas(16) u16   qb[32 * 72];
    __shared__ alignas(16) u16   kb[32 * 72];
    __shared__ alignas(16) u16   avaT[64 * 40];  // ava^T[e][i]
    __shared__ alignas(16) u16   diffb[32 * 72];
    __shared__ alignas(16) u16   wb[32 * 40];
    __shared__ alignas(16) float S32[32 * 68];
    __shared__ alignas(16) u16   Sb[32 * 72];

    // ---- stage 0: staged inputs (padded rows: 17 uint4 = 136 bf16) + WgT
    if (t < 512) {
        const int r = t >> 4, c = t & 15;
        ((uint4*)sSE)[r * 17 + c] = ((const uint4*)(seb + b * 4096))[t];
        ((uint4*)sXP)[r * 17 + c] = ((const uint4*)(xpb + b * 4096))[t];
    } else {
        const int t2 = t - 512, r = t2 >> 4, c = t2 & 15;
        ((uint4*)sXA)[r * 17 + c] = ((const uint4*)(xab + b * 4096))[t2];
    }
    {
        const float4 f4 = ((const float4*)(W_f1 + h * 4096))[t];
        const int ee = t >> 4, c4 = (t & 15) * 4;
        const float g = ln_g[h * 64 + ee];
        WgT[(c4 + 0) * 72 + ee] = f2bf(g * f4.x);
        WgT[(c4 + 1) * 72 + ee] = f2bf(g * f4.y);
        WgT[(c4 + 2) * 72 + ee] = f2bf(g * f4.z);
        WgT[(c4 + 3) * 72 + ee] = f2bf(g * f4.w);
    }
    __syncthreads();

    // ---- phase A: M1 (q,k,ava,avp) — 2 tiles/wave, K=128
    f32x4 acc[2];
    #pragma unroll
    for (int p = 0; p < 2; p++) {
        const int tau = wave * 2 + p;
        const int mat = tau >> 3;
        const int mt  = (tau >> 2) & 1, nt = tau & 3;
        const u16* X  = (mat <= 1) ? sSE : (mat == 2 ? sXA : sXP);
        const int widx = (mat == 0) ? 0 : (mat == 1 ? 1 : 2);
        const int arow = mt * 16 + l16;
        const u16* wsrc = wTb + ((h * 3 + widx) * 64 + nt * 16 + l16) * 128;
        f32x4 a = {0.f, 0.f, 0.f, 0.f};
        #pragma unroll
        for (int ks = 0; ks < 4; ks++) {
            const bf16x8 af = *(const bf16x8*)&X[arow * 136 + ks * 32 + q16 * 8];
            const bf16x8 bf = *(const bf16x8*)&wsrc[ks * 32 + q16 * 8];
            a = __builtin_amdgcn_mfma_f32_16x16x32_bf16(af, bf, a, 0, 0, 0);
        }
        acc[p] = a;
    }
    #pragma unroll
    for (int p = 0; p < 2; p++) {
        const int tau = wave * 2 + p;
        const int mat = tau >> 3;
        const int mt  = (tau >> 2) & 1, nt = tau & 3;
        const int c   = nt * 16 + l16;
        const int r0  = mt * 16 + q16 * 4;
        if (mat == 0) {
            #pragma unroll
            for (int v = 0; v < 4; v++) qb[(r0 + v) * 72 + c] = f2bf(acc[p][v]);
        } else if (mat == 1) {
            #pragma unroll
            for (int v = 0; v < 4; v++) kb[(r0 + v) * 72 + c] = f2bf(acc[p][v]);
        } else if (mat == 2) {
            #pragma unroll
            for (int v = 0; v < 4; v++) avaT[c * 40 + (r0 + v)] = f2bf(acc[p][v]);
        } // mat==3 (avp) held in regs
    }
    __syncthreads();

    // ---- phase B: scores+softmax (waves 0-1) | GW (wave 2) | diff (waves 12-15)
    if (wave < 2) {
        const int mt = wave;
        f32x4 s0 = {0.f,0.f,0.f,0.f}, s1 = {0.f,0.f,0.f,0.f};
        #pragma unroll
        for (int ks = 0; ks < 2; ks++) {
            const bf16x8 af = *(const bf16x8*)&qb[(mt * 16 + l16) * 72 + ks * 32 + q16 * 8];
            const bf16x8 b0 = *(const bf16x8*)&kb[l16 * 72 + ks * 32 + q16 * 8];
            const bf16x8 b1 = *(const bf16x8*)&kb[(16 + l16) * 72 + ks * 32 + q16 * 8];
            s0 = __builtin_amdgcn_mfma_f32_16x16x32_bf16(af, b0, s0, 0, 0, 0);
            s1 = __builtin_amdgcn_mfma_f32_16x16x32_bf16(af, b1, s1, 0, 0, 0);
        }
        #pragma unroll
        for (int v = 0; v < 4; v++) {
            float a0 = s0[v] * 0.125f, a1 = s1[v] * 0.125f;
            float mx = fmaxf(a0, a1);
            #pragma unroll
            for (int m = 1; m < 16; m <<= 1) mx = fmaxf(mx, __shfl_xor(mx, m));
            float e0 = __expf(a0 - mx), e1 = __expf(a1 - mx);
            float sm = e0 + e1;
            #pragma unroll
            for (int m = 1; m < 16; m <<= 1) sm += __shfl_xor(sm, m);
            const float inv = 1.f / sm;
            e0 *= inv; e1 *= inv;
            const int i = mt * 16 + q16 * 4 + v;
            wb[i * 40 + l16]      = f2bf(e0);
            wb[i * 40 + 16 + l16] = f2bf(e1);
            w_out[(bh * 32 + i) * 32 + l16]      = e0;
            w_out[(bh * 32 + i) * 32 + 16 + l16] = e1;
        }
    } else if (wave == 2) {
        // GW[h,c] fp32-exact from global
        const int c = e;
        const float* wf = W_f1 + h * 4096;
        float g = 0.f;
        #pragma unroll 4
        for (int ee = 0; ee < 64; ee++) g += ln_g[h * 64 + ee] * wf[ee * 64 + c];
        GW[h * 64 + c] = g;
    } else if (wave >= 12) {
        #pragma unroll
        for (int p = 0; p < 2; p++) {
            const int tau = wave * 2 + p;
            const int mt  = (tau >> 2) & 1, nt = tau & 3;
            const int c   = nt * 16 + l16;
            const int r0  = mt * 16 + q16 * 4;
            #pragma unroll
            for (int v = 0; v < 4; v++) {
                const float av = bf2f(avaT[c * 40 + (r0 + v)]);
                diffb[(r0 + v) * 72 + c] = f2bf(acc[p][v] - av);
            }
        }
    }
    __syncthreads();

    // ---- phase C: S = w@ava (waves 0-7, K=32) | DG = diff@Wg (waves 8-15)
    if (wave < 8) {
        const int mt = wave >> 2, nt = wave & 3;
        const bf16x8 af = *(const bf16x8*)&wb[(mt * 16 + l16) * 40 + q16 * 8];
        const bf16x8 bf = *(const bf16x8*)&avaT[(nt * 16 + l16) * 40 + q16 * 8];
        f32x4 a = {0.f, 0.f, 0.f, 0.f};
        a = __builtin_amdgcn_mfma_f32_16x16x32_bf16(af, bf, a, 0, 0, 0);
        const int c = nt * 16 + l16, r0 = mt * 16 + q16 * 4;
        #pragma unroll
        for (int v = 0; v < 4; v++) {
            S32[(r0 + v) * 68 + c] = a[v];
            Sb[(r0 + v) * 72 + c]  = f2bf(a[v]);
        }
    } else {
        const int w8 = wave - 8;
        const int mt = w8 >> 2, nt = w8 & 3;
        f32x4 a = {0.f, 0.f, 0.f, 0.f};
        #pragma unroll
        for (int ks = 0; ks < 2; ks++) {
            const bf16x8 af = *(const bf16x8*)&diffb[(mt * 16 + l16) * 72 + ks * 32 + q16 * 8];
            const bf16x8 bf = *(const bf16x8*)&WgT[(nt * 16 + l16) * 72 + ks * 32 + q16 * 8];
            a = __builtin_amdgcn_mfma_f32_16x16x32_bf16(af, bf, a, 0, 0, 0);
        }
        const int c = nt * 16 + l16, r0 = mt * 16 + q16 * 4;
        #pragma unroll
        for (int v = 0; v < 4; v++)
            DG[(bh * 32 + r0 + v) * 64 + c] = a[v];
    }
    if (t < 32) {   // sumD/sumD2 from bf16 diff (fp32 accum)
        float s1 = 0.f, s2 = 0.f;
        #pragma unroll
        for (int e8 = 0; e8 < 8; e8++) {
            const uint4 u = *(const uint4*)&diffb[t * 72 + e8 * 8];
            const unsigned int uu[4] = {u.x, u.y, u.z, u.w};
            #pragma unroll
            for (int q = 0; q < 4; q++) {
                const float fl = __uint_as_float(uu[q] << 16);
                const float fh = __uint_as_float(uu[q] & 0xffff0000u);
                s1 += fl + fh;
                s2 += fl * fl + fh * fh;
            }
        }
        sumD[bh * 32 + t] = s1; sumD2[bh * 32 + t] = s2;
    }
    __syncthreads();

    // ---- phase D: dotSD (waves 0-3) | SG (waves 8-15) | sumS (t in [256,288))
    if (wave < 4) {
        const int mt = wave >> 1, nt = wave & 1;
        f32x4 a = {0.f, 0.f, 0.f, 0.f};
        #pragma unroll
        for (int ks = 0; ks < 2; ks++) {
            const bf16x8 af = *(const bf16x8*)&Sb[(mt * 16 + l16) * 72 + ks * 32 + q16 * 8];
            const bf16x8 bf = *(const bf16x8*)&diffb[(nt * 16 + l16) * 72 + ks * 32 + q16 * 8];
            a = __builtin_amdgcn_mfma_f32_16x16x32_bf16(af, bf, a, 0, 0, 0);
        }
        const int j = nt * 16 + l16, r0 = mt * 16 + q16 * 4;
        #pragma unroll
        for (int v = 0; v < 4; v++)
            dotSD[(bh * 32 + r0 + v) * 32 + j] = a[v];
    } else if (wave >= 8) {
        const int w8 = wave - 8;
        const int mt = w8 >> 2, nt = w8 & 3;
        f32x4 a = {0.f, 0.f, 0.f, 0.f};
        #pragma unroll
        for (int ks = 0; ks < 2; ks++) {
            const bf16x8 af = *(const bf16x8*)&Sb[(mt * 16 + l16) * 72 + ks * 32 + q16 * 8];
            const bf16x8 bf = *(const bf16x8*)&WgT[(nt * 16 + l16) * 72 + ks * 32 + q16 * 8];
            a = __builtin_amdgcn_mfma_f32_16x16x32_bf16(af, bf, a, 0, 0, 0);
        }
        const int c = nt * 16 + l16, r0 = mt * 16 + q16 * 4;
        #pragma unroll
        for (int v = 0; v < 4; v++)
            SG[(bh * 32 + r0 + v) * 64 + c] = a[v];
    } else if (t >= 256 && t < 288) {
        const int r = t - 256;
        float s1 = 0.f, s2 = 0.f;
        #pragma unroll
        for (int e4 = 0; e4 < 16; e4++) {
            const float4 v4 = *(const float4*)&S32[r * 68 + e4 * 4];
            s1 += v4.x + v4.y + v4.z + v4.w;
            s2 += v4.x * v4.x + v4.y * v4.y + v4.z * v4.z + v4.w * v4.w;
        }
        sumS[bh * 32 + r] = s1; sumS2[bh * 32 + r] = s2;
    }
}

// ---------------------------------------------------------------------------
// Kernel C (512 blocks: b x 4 i-groups of 8; 256 threads) — unchanged
// ---------------------------------------------------------------------------
__global__ __launch_bounds__(256) void kC(
    const float* __restrict__ SG, const float* __restrict__ DG,
    const float* __restrict__ sumS, const float* __restrict__ sumS2,
    const float* __restrict__ sumD, const float* __restrict__ sumD2,
    const float* __restrict__ dotSD, const float* __restrict__ w_all,
    const float* __restrict__ GW, const float* __restrict__ ln_b,
    const float* __restrict__ W_f1, const float* __restrict__ W_f2,
    float* __restrict__ value)
{
    const int blk = blockIdx.x;
    const int b   = blk >> 2;
    const int i0  = (blk & 3) * 8;
    const int t   = threadIdx.x;

    __shared__ float SGs[8][256];
    __shared__ float GWs[256];
    __shared__ float BWs[64], wf2s[64];
    __shared__ float bwp[4][64];
    __shared__ float w_s[4][8][32];
    __shared__ float mu_s[4][8][32];
    __shared__ float inv_s[4][8][32];

    {
        const int c = t & 63, qq = t >> 6;
        float bacc = 0.f;
        #pragma unroll 4
        for (int r = 0; r < 64; r++)
            bacc += ln_b[qq * 64 + r] * W_f1[(qq * 64 + r) * 64 + c];
        bwp[qq][c] = bacc;
    }

    GWs[t] = GW[t];
    if (t < 64) wf2s[t] = W_f2[t];
    for (int idx4 = t; idx4 < 512; idx4 += 256) {
        const int ii  = idx4 >> 6;
        const int hc4 = idx4 & 63;
        const int hh  = hc4 >> 4, c4 = (hc4 & 15) * 4;
        ((float4*)&SGs[ii][0])[hc4] =
            *(const float4*)&SG[((b * 4 + hh) * 32 + i0 + ii) * 64 + c4];
    }
    for (int idx = t; idx < 1024; idx += 256) {
        const int hh = idx >> 8, ii = (idx >> 5) & 7, j = idx & 31;
        const int hi = (b * 4 + hh) * 32 + (i0 + ii);
        const int hj = (b * 4 + hh) * 32 + j;
        const float wv  = w_all[hi * 32 + j];
        const float dsd = dotSD[hi * 32 + j];
        const float mu  = (sumS[hi] + wv * sumD[hj]) * (1.f / 64.f);
        const float e2  = (sumS2[hi] + 2.f * wv * dsd + wv * wv * sumD2[hj]) * (1.f / 64.f);
        const float var = fmaxf(e2 - mu * mu, 0.f);
        w_s[hh][ii][j]   = wv;
        mu_s[hh][ii][j]  = mu;
        inv_s[hh][ii][j] = rsqrtf(var + LN_EPS);
    }
    __syncthreads();
    if (t < 64) BWs[t] = bwp[0][t] + bwp[1][t] + bwp[2][t] + bwp[3][t];
    __syncthreads();

    const int w0 = t >> 6;
    const int e  = t & 63;
    const float GW0 = GWs[e],       GW1 = GWs[64 + e];
    const float GW2 = GWs[128 + e], GW3 = GWs[192 + e];
    const float bwr = BWs[e], f2 = wf2s[e];
    const float* DGb = DG + b * H * N * 64;

    for (int jb = 0; jb < 8; jb++) {
        const int j = jb * 4 + w0;
        const float d0 = DGb[(0 * 32 + j) * 64 + e];
        const float d1 = DGb[(1 * 32 + j) * 64 + e];
        const float d2 = DGb[(2 * 32 + j) * 64 + e];
        const float d3 = DGb[(3 * 32 + j) * 64 + e];
        #pragma unroll
        for (int ii = 0; ii < 8; ii++) {
            float z = bwr;
            z += inv_s[0][ii][j] * (SGs[ii][e]       + w_s[0][ii][j] * d0 - mu_s[0][ii][j] * GW0);
            z += inv_s[1][ii][j] * (SGs[ii][64 + e]  + w_s[1][ii][j] * d1 - mu_s[1][ii][j] * GW1);
            z += inv_s[2][ii][j] * (SGs[ii][128 + e] + w_s[2][ii][j] * d2 - mu_s[2][ii][j] * GW2);
            z += inv_s[3][ii][j] * (SGs[ii][192 + e] + w_s[3][ii][j] * d3 - mu_s[3][ii][j] * GW3);
            float p = leaky(z) * f2;
            #pragma unroll
            for (int m = 32; m; m >>= 1) p += __shfl_xor(p, m);
            if (e == 0) value[(b * 32 + i0 + ii) * 32 + j] = p;
        }
    }
}

extern "C" void kernel_launch(void* const* d_in, const int* in_sizes, int n_in,
                              void* d_out, int out_size, void* d_ws, size_t ws_size,
                              hipStream_t stream)
{
    const float* states   = (const float*)d_in[0];
    const float* policies = (const float*)d_in[1];
    const float* actions  = (const float*)d_in[2];
    const float* W_se     = (const float*)d_in[3];
    const float* b_se     = (const float*)d_in[4];
    const float* W_sape   = (const float*)d_in[5];
    const float* b_sape   = (const float*)d_in[6];
    const float* Wk       = (const float*)d_in[7];
    const float* Wq       = (const float*)d_in[8];
    const float* Wv       = (const float*)d_in[9];
    const float* ln_g     = (const float*)d_in[10];
    const float* ln_b     = (const float*)d_in[11];
    const float* W_f1     = (const float*)d_in[12];
    const float* W_f2     = (const float*)d_in[13];

    float* out_value = (float*)d_out;
    float* out_w     = out_value + B * N * N;

    float* ws    = (float*)d_ws;
    float* SG    = ws;                       // 1,048,576
    float* DG    = SG    + 1048576;          // 1,048,576
    float* sumS  = DG    + 1048576;          // 16,384
    float* sumS2 = sumS  + 16384;
    float* sumD  = sumS2 + 16384;
    float* sumD2 = sumD  + 16384;
    float* dotSD = sumD2 + 16384;            // 524,288
    float* GW    = dotSD + 524288;           // 256
    u16*   seb   = (u16*)(GW + 256);         // 524,288 u16
    u16*   xab   = seb + 524288;
    u16*   xpb   = xab + 524288;
    u16*   wTb   = xpb + 524288;             // 98,304 u16

    kA<<<516, 128, 0, stream>>>(states, policies, actions, W_se, b_se,
                                W_sape, b_sape, Wk, Wq, Wv,
                                seb, xab, xpb, wTb);
    kB<<<B * H, 1024, 0, stream>>>(seb, xab, xpb, wTb, W_f1, ln_g, out_w,
                                   SG, DG, sumS, sumS2, sumD, sumD2, dotSD, GW);
    kC<<<512, 256, 0, stream>>>(SG, DG, sumS, sumS2, sumD, sumD2, dotSD,
                                out_w, GW, ln_b, W_f1, W_f2, out_value);
}

// Round 9
// 146.872 us; speedup vs baseline: 1.3407x; 1.0506x over previous
//
#include <hip/hip_runtime.h>
#include <hip/hip_bf16.h>

#define B 128
#define N 32
#define DO 128
#define NA 16
#define H 4
#define DK 64
#define DV 64
#define LN_EPS 1e-5f
#define NEG_SLOPE 0.01f

typedef unsigned short u16;
typedef __attribute__((ext_vector_type(8))) short bf16x8;
typedef __attribute__((ext_vector_type(4))) float f32x4;

__device__ __forceinline__ float leaky(float x) {
    return x >= 0.f ? x : NEG_SLOPE * x;
}

__device__ __forceinline__ u16 f2bf(float x) {
    union { float f; unsigned int u; } v; v.f = x;
    unsigned int r = (v.u + 0x7FFF + ((v.u >> 16) & 1)) >> 16;
    return (u16)r;
}

__device__ __forceinline__ float bf2f(u16 x) {
    union { unsigned int u; float f; } v; v.u = ((unsigned int)x) << 16;
    return v.f;
}

// ---------------------------------------------------------------------------
// kP: one-shot weight prep, 7 blocks x 256 threads.
//  blk 0-3 (h): Wq/Wk/Wv head h -> bf16 wTb[(h*3+m)*8192], [n][k=128]
//  blk 4: W_se -> bf16 wseT[n][k=128]
//  blk 5: W_sape rows 0-127 -> wsapeT[n][128]; rows 128-143 -> sapeTail[n][32] (zero-pad)
//  blk 6: wTg[(h*64+c)*64+e] = bf16(ln_g*W_f1); GW fp32; BW fp32
// ---------------------------------------------------------------------------
__global__ __launch_bounds__(256) void kP(
    const float* __restrict__ Wk, const float* __restrict__ Wq,
    const float* __restrict__ Wv, const float* __restrict__ W_se,
    const float* __restrict__ W_sape, const float* __restrict__ ln_g,
    const float* __restrict__ ln_b, const float* __restrict__ W_f1,
    u16* __restrict__ wTb, u16* __restrict__ wseT, u16* __restrict__ wsapeT,
    u16* __restrict__ sapeTail, u16* __restrict__ wTg,
    float* __restrict__ GW, float* __restrict__ BW)
{
    const int blk = blockIdx.x;
    const int t   = threadIdx.x;
    __shared__ float wls[8192];

    if (blk < 4) {
        const int hh = blk;
        for (int m = 0; m < 3; m++) {
            const float* src = (m == 0 ? Wq : (m == 1 ? Wk : Wv)) + hh * 8192;
            for (int idx = t; idx < 2048; idx += 256)
                ((float4*)wls)[idx] = ((const float4*)src)[idx];
            __syncthreads();
            u16* dst = wTb + (hh * 3 + m) * 8192;
            for (int idx = t; idx < 8192; idx += 256) {
                const int n = idx >> 7, k = idx & 127;
                dst[idx] = f2bf(wls[k * 64 + n]);
            }
            __syncthreads();
        }
    } else if (blk == 4 || blk == 5) {
        const float* src = (blk == 4) ? W_se : W_sape;
        u16* dst = (blk == 4) ? wseT : wsapeT;
        for (int chunk = 0; chunk < 2; chunk++) {
            const int k0 = chunk * 64;
            for (int idx = t; idx < 2048; idx += 256)
                ((float4*)wls)[idx] = ((const float4*)(src + k0 * 128))[idx];
            __syncthreads();
            for (int idx = t; idx < 8192; idx += 256) {
                const int n = idx >> 6, kk = idx & 63;
                dst[n * 128 + k0 + kk] = f2bf(wls[kk * 128 + n]);
            }
            __syncthreads();
        }
        if (blk == 5) {
            for (int idx = t; idx < 2048; idx += 256)
                wls[idx] = W_sape[128 * 128 + idx];
            __syncthreads();
            for (int idx = t; idx < 4096; idx += 256) {
                const int n = idx >> 5, kk = idx & 31;
                sapeTail[n * 32 + kk] = (kk < 16) ? f2bf(wls[kk * 128 + n]) : (u16)0;
            }
        }
    } else {
        for (int idx = t; idx < 16384; idx += 256) {
            const int hh = idx >> 12, c = (idx >> 6) & 63, ee = idx & 63;
            wTg[idx] = f2bf(ln_g[hh * 64 + ee] * W_f1[(hh * 64 + ee) * 64 + c]);
        }
        {   // GW fp32-exact
            const int hh = t >> 6, c = t & 63;
            float g = 0.f;
            #pragma unroll 4
            for (int ee = 0; ee < 64; ee++)
                g += ln_g[hh * 64 + ee] * W_f1[(hh * 64 + ee) * 64 + c];
            GW[t] = g;
        }
        {   // BW fp32-exact via partials
            const int c = t & 63, qq = t >> 6;
            float bacc = 0.f;
            #pragma unroll 4
            for (int r = 0; r < 64; r++)
                bacc += ln_b[qq * 64 + r] * W_f1[(qq * 64 + r) * 64 + c];
            wls[qq * 64 + c] = bacc;
        }
        __syncthreads();
        if (t < 64) BW[t] = wls[t] + wls[64 + t] + wls[128 + t] + wls[192 + t];
    }
}

// ---------------------------------------------------------------------------
// Kernel B: 1024 threads; kA fused as phase -1 (se/xa/xp never hit global).
// Phases: stage | -1: se/xa/xp MFMA | A: q,k,ava,avp | B: softmax / diff |
//         C: S=w@ava + sumD / DG | D: dotSD / SG / sumS.  LDS 72,192B.
// ---------------------------------------------------------------------------
__global__ __launch_bounds__(1024, 8) void kB(
    const float* __restrict__ states, const float* __restrict__ actions,
    const float* __restrict__ policies,
    const float* __restrict__ b_se, const float* __restrict__ b_sape,
    const u16* __restrict__ wTb, const u16* __restrict__ wseT,
    const u16* __restrict__ wsapeT, const u16* __restrict__ sapeTail,
    const u16* __restrict__ wTg,
    float* __restrict__ w_out,
    float* __restrict__ SG, float* __restrict__ DG,
    float* __restrict__ sumS, float* __restrict__ sumS2,
    float* __restrict__ sumD, float* __restrict__ sumD2,
    float* __restrict__ dotSD)
{
    const int bh   = blockIdx.x;
    const int b    = bh >> 2;
    const int h    = bh & 3;
    const int t    = threadIdx.x;
    const int wave = t >> 6;
    const int e    = t & 63;
    const int q16  = e >> 4;
    const int l16  = e & 15;

    __shared__ alignas(16) u16   sST[32 * 136];
    __shared__ alignas(16) u16   actA[32 * 40];
    __shared__ alignas(16) u16   polA[32 * 40];
    __shared__ alignas(16) u16   sSE[32 * 136];
    __shared__ alignas(16) u16   sXA[32 * 136];
    __shared__ alignas(16) u16   sXP[32 * 136];
    __shared__ alignas(16) u16   qb[32 * 72];
    __shared__ alignas(16) u16   kb[32 * 72];
    __shared__ alignas(16) u16   avaT[64 * 40];
    __shared__ alignas(16) u16   diffb[32 * 72];
    __shared__ alignas(16) u16   wb[32 * 40];
    __shared__ alignas(16) float S32[32 * 68];
    __shared__ alignas(16) u16   Sb[32 * 72];

    // ---- stage: states/actions/policies -> bf16 LDS
    {
        const int r = t >> 5, c4 = (t & 31) * 4;
        const float4 s4 = *(const float4*)&states[(b * 32 + r) * 128 + c4];
        ushort4 u;
        u.x = f2bf(s4.x); u.y = f2bf(s4.y); u.z = f2bf(s4.z); u.w = f2bf(s4.w);
        *(ushort4*)&sST[r * 136 + c4] = u;
    }
    if (t < 512) {
        const int r = t >> 4, c = t & 15;
        actA[r * 40 + c]      = f2bf(actions[(b * 32 + r) * 16 + c]);
        actA[r * 40 + 16 + c] = 0;
    } else {
        const int t2 = t - 512, r = t2 >> 4, c = t2 & 15;
        polA[r * 40 + c]      = f2bf(policies[(b * 32 + r) * 16 + c]);
        polA[r * 40 + 16 + c] = 0;
    }
    __syncthreads();

    // ---- phase -1: se/xa/xp (wave = tile: mt=wave>>3, nt=wave&7)
    {
        const int mt = wave >> 3, nt = wave & 7;
        const int arow = mt * 16 + l16;
        const int bcol = nt * 16 + l16;
        f32x4 a_se = {0.f,0.f,0.f,0.f}, a_sp = {0.f,0.f,0.f,0.f};
        f32x4 a_oa = {0.f,0.f,0.f,0.f}, a_op = {0.f,0.f,0.f,0.f};
        const u16* bse_p = wseT + bcol * 128;
        const u16* bsp_p = wsapeT + bcol * 128;
        #pragma unroll
        for (int ks = 0; ks < 4; ks++) {
            const bf16x8 af = *(const bf16x8*)&sST[arow * 136 + ks * 32 + q16 * 8];
            a_se = __builtin_amdgcn_mfma_f32_16x16x32_bf16(
                af, *(const bf16x8*)&bse_p[ks * 32 + q16 * 8], a_se, 0, 0, 0);
            a_sp = __builtin_amdgcn_mfma_f32_16x16x32_bf16(
                af, *(const bf16x8*)&bsp_p[ks * 32 + q16 * 8], a_sp, 0, 0, 0);
        }
        const bf16x8 bt = *(const bf16x8*)&sapeTail[bcol * 32 + q16 * 8];
        a_oa = __builtin_amdgcn_mfma_f32_16x16x32_bf16(
            *(const bf16x8*)&actA[arow * 40 + q16 * 8], bt, a_oa, 0, 0, 0);
        a_op = __builtin_amdgcn_mfma_f32_16x16x32_bf16(
            *(const bf16x8*)&polA[arow * 40 + q16 * 8], bt, a_op, 0, 0, 0);
        const float bse_c = b_se[bcol];
        const float bsp_c = b_sape[bcol];
        const int r0 = mt * 16 + q16 * 4;
        #pragma unroll
        for (int v = 0; v < 4; v++) {
            sSE[(r0 + v) * 136 + bcol] = f2bf(leaky(a_se[v] + bse_c));
            sXA[(r0 + v) * 136 + bcol] = f2bf(leaky(a_sp[v] + a_oa[v] + bsp_c));
            sXP[(r0 + v) * 136 + bcol] = f2bf(leaky(a_sp[v] + a_op[v] + bsp_c));
        }
    }
    __syncthreads();

    // ---- phase A: q,k,ava,avp — 2 tiles/wave, K=128
    f32x4 acc[2];
    #pragma unroll
    for (int p = 0; p < 2; p++) {
        const int tau = wave * 2 + p;
        const int mat = tau >> 3;
        const int mt  = (tau >> 2) & 1, nt = tau & 3;
        const u16* X  = (mat <= 1) ? sSE : (mat == 2 ? sXA : sXP);
        const int widx = (mat == 0) ? 0 : (mat == 1 ? 1 : 2);
        const int arow = mt * 16 + l16;
        const u16* wsrc = wTb + ((h * 3 + widx) * 64 + nt * 16 + l16) * 128;
        f32x4 a = {0.f, 0.f, 0.f, 0.f};
        #pragma unroll
        for (int ks = 0; ks < 4; ks++) {
            const bf16x8 af = *(const bf16x8*)&X[arow * 136 + ks * 32 + q16 * 8];
            const bf16x8 bf = *(const bf16x8*)&wsrc[ks * 32 + q16 * 8];
            a = __builtin_amdgcn_mfma_f32_16x16x32_bf16(af, bf, a, 0, 0, 0);
        }
        acc[p] = a;
    }
    #pragma unroll
    for (int p = 0; p < 2; p++) {
        const int tau = wave * 2 + p;
        const int mat = tau >> 3;
        const int mt  = (tau >> 2) & 1, nt = tau & 3;
        const int c   = nt * 16 + l16;
        const int r0  = mt * 16 + q16 * 4;
        if (mat == 0) {
            #pragma unroll
            for (int v = 0; v < 4; v++) qb[(r0 + v) * 72 + c] = f2bf(acc[p][v]);
        } else if (mat == 1) {
            #pragma unroll
            for (int v = 0; v < 4; v++) kb[(r0 + v) * 72 + c] = f2bf(acc[p][v]);
        } else if (mat == 2) {
            #pragma unroll
            for (int v = 0; v < 4; v++) avaT[c * 40 + (r0 + v)] = f2bf(acc[p][v]);
        } // mat==3 (avp) held in regs
    }
    __syncthreads();

    // ---- phase B: scores+softmax (waves 0-1) | diff (waves 12-15)
    if (wave < 2) {
        const int mt = wave;
        f32x4 s0 = {0.f,0.f,0.f,0.f}, s1 = {0.f,0.f,0.f,0.f};
        #pragma unroll
        for (int ks = 0; ks < 2; ks++) {
            const bf16x8 af = *(const bf16x8*)&qb[(mt * 16 + l16) * 72 + ks * 32 + q16 * 8];
            const bf16x8 b0 = *(const bf16x8*)&kb[l16 * 72 + ks * 32 + q16 * 8];
            const bf16x8 b1 = *(const bf16x8*)&kb[(16 + l16) * 72 + ks * 32 + q16 * 8];
            s0 = __builtin_amdgcn_mfma_f32_16x16x32_bf16(af, b0, s0, 0, 0, 0);
            s1 = __builtin_amdgcn_mfma_f32_16x16x32_bf16(af, b1, s1, 0, 0, 0);
        }
        #pragma unroll
        for (int v = 0; v < 4; v++) {
            float a0 = s0[v] * 0.125f, a1 = s1[v] * 0.125f;
            float mx = fmaxf(a0, a1);
            #pragma unroll
            for (int m = 1; m < 16; m <<= 1) mx = fmaxf(mx, __shfl_xor(mx, m));
            float e0 = __expf(a0 - mx), e1 = __expf(a1 - mx);
            float sm = e0 + e1;
            #pragma unroll
            for (int m = 1; m < 16; m <<= 1) sm += __shfl_xor(sm, m);
            const float inv = 1.f / sm;
            e0 *= inv; e1 *= inv;
            const int i = mt * 16 + q16 * 4 + v;
            wb[i * 40 + l16]      = f2bf(e0);
            wb[i * 40 + 16 + l16] = f2bf(e1);
            w_out[(bh * 32 + i) * 32 + l16]      = e0;
            w_out[(bh * 32 + i) * 32 + 16 + l16] = e1;
        }
    } else if (wave >= 12) {
        #pragma unroll
        for (int p = 0; p < 2; p++) {
            const int tau = wave * 2 + p;
            const int mt  = (tau >> 2) & 1, nt = tau & 3;
            const int c   = nt * 16 + l16;
            const int r0  = mt * 16 + q16 * 4;
            #pragma unroll
            for (int v = 0; v < 4; v++) {
                const float av = bf2f(avaT[c * 40 + (r0 + v)]);
                diffb[(r0 + v) * 72 + c] = f2bf(acc[p][v] - av);
            }
        }
    }
    __syncthreads();

    // ---- phase C: S = w@ava (waves 0-7) | DG = diff@Wg (waves 8-15)
    if (wave < 8) {
        const int mt = wave >> 2, nt = wave & 3;
        const bf16x8 af = *(const bf16x8*)&wb[(mt * 16 + l16) * 40 + q16 * 8];
        const bf16x8 bf = *(const bf16x8*)&avaT[(nt * 16 + l16) * 40 + q16 * 8];
        f32x4 a = {0.f, 0.f, 0.f, 0.f};
        a = __builtin_amdgcn_mfma_f32_16x16x32_bf16(af, bf, a, 0, 0, 0);
        const int c = nt * 16 + l16, r0 = mt * 16 + q16 * 4;
        #pragma unroll
        for (int v = 0; v < 4; v++) {
            S32[(r0 + v) * 68 + c] = a[v];
            Sb[(r0 + v) * 72 + c]  = f2bf(a[v]);
        }
    } else {
        const int w8 = wave - 8;
        const int mt = w8 >> 2, nt = w8 & 3;
        const u16* wgp = wTg + (h * 64 + nt * 16 + l16) * 64;
        f32x4 a = {0.f, 0.f, 0.f, 0.f};
        #pragma unroll
        for (int ks = 0; ks < 2; ks++) {
            const bf16x8 af = *(const bf16x8*)&diffb[(mt * 16 + l16) * 72 + ks * 32 + q16 * 8];
            const bf16x8 bf = *(const bf16x8*)&wgp[ks * 32 + q16 * 8];
            a = __builtin_amdgcn_mfma_f32_16x16x32_bf16(af, bf, a, 0, 0, 0);
        }
        const int c = nt * 16 + l16, r0 = mt * 16 + q16 * 4;
        #pragma unroll
        for (int v = 0; v < 4; v++)
            DG[(bh * 32 + r0 + v) * 64 + c] = a[v];
    }
    if (t < 32) {   // sumD/sumD2 from bf16 diff (fp32 accum)
        float s1 = 0.f, s2 = 0.f;
        #pragma unroll
        for (int e8 = 0; e8 < 8; e8++) {
            const uint4 u = *(const uint4*)&diffb[t * 72 + e8 * 8];
            const unsigned int uu[4] = {u.x, u.y, u.z, u.w};
            #pragma unroll
            for (int q = 0; q < 4; q++) {
                const float fl = __uint_as_float(uu[q] << 16);
                const float fh = __uint_as_float(uu[q] & 0xffff0000u);
                s1 += fl + fh;
                s2 += fl * fl + fh * fh;
            }
        }
        sumD[bh * 32 + t] = s1; sumD2[bh * 32 + t] = s2;
    }
    __syncthreads();

    // ---- phase D: dotSD (waves 0-3) | SG (waves 8-15) | sumS (t in [256,288))
    if (wave < 4) {
        const int mt = wave >> 1, nt = wave & 1;
        f32x4 a = {0.f, 0.f, 0.f, 0.f};
        #pragma unroll
        for (int ks = 0; ks < 2; ks++) {
            const bf16x8 af = *(const bf16x8*)&Sb[(mt * 16 + l16) * 72 + ks * 32 + q16 * 8];
            const bf16x8 bf = *(const bf16x8*)&diffb[(nt * 16 + l16) * 72 + ks * 32 + q16 * 8];
            a = __builtin_amdgcn_mfma_f32_16x16x32_bf16(af, bf, a, 0, 0, 0);
        }
        const int j = nt * 16 + l16, r0 = mt * 16 + q16 * 4;
        #pragma unroll
        for (int v = 0; v < 4; v++)
            dotSD[(bh * 32 + r0 + v) * 32 + j] = a[v];
    } else if (wave >= 8) {
        const int w8 = wave - 8;
        const int mt = w8 >> 2, nt = w8 & 3;
        const u16* wgp = wTg + (h * 64 + nt * 16 + l16) * 64;
        f32x4 a = {0.f, 0.f, 0.f, 0.f};
        #pragma unroll
        for (int ks = 0; ks < 2; ks++) {
            const bf16x8 af = *(const bf16x8*)&Sb[(mt * 16 + l16) * 72 + ks * 32 + q16 * 8];
            const bf16x8 bf = *(const bf16x8*)&wgp[ks * 32 + q16 * 8];
            a = __builtin_amdgcn_mfma_f32_16x16x32_bf16(af, bf, a, 0, 0, 0);
        }
        const int c = nt * 16 + l16, r0 = mt * 16 + q16 * 4;
        #pragma unroll
        for (int v = 0; v < 4; v++)
            SG[(bh * 32 + r0 + v) * 64 + c] = a[v];
    } else if (t >= 256 && t < 288) {
        const int r = t - 256;
        float s1 = 0.f, s2 = 0.f;
        #pragma unroll
        for (int e4 = 0; e4 < 16; e4++) {
            const float4 v4 = *(const float4*)&S32[r * 68 + e4 * 4];
            s1 += v4.x + v4.y + v4.z + v4.w;
            s2 += v4.x * v4.x + v4.y * v4.y + v4.z * v4.z + v4.w * v4.w;
        }
        sumS[bh * 32 + r] = s1; sumS2[bh * 32 + r] = s2;
    }
}

// ---------------------------------------------------------------------------
// Kernel C (512 blocks: b x 4 i-groups of 8; 256 threads); BW precomputed
// ---------------------------------------------------------------------------
__global__ __launch_bounds__(256) void kC(
    const float* __restrict__ SG, const float* __restrict__ DG,
    const float* __restrict__ sumS, const float* __restrict__ sumS2,
    const float* __restrict__ sumD, const float* __restrict__ sumD2,
    const float* __restrict__ dotSD, const float* __restrict__ w_all,
    const float* __restrict__ GW, const float* __restrict__ BW,
    const float* __restrict__ W_f2, float* __restrict__ value)
{
    const int blk = blockIdx.x;
    const int b   = blk >> 2;
    const int i0  = (blk & 3) * 8;
    const int t   = threadIdx.x;

    __shared__ float SGs[8][256];
    __shared__ float GWs[256];
    __shared__ float BWs[64], wf2s[64];
    __shared__ float w_s[4][8][32];
    __shared__ float mu_s[4][8][32];
    __shared__ float inv_s[4][8][32];

    GWs[t] = GW[t];
    if (t < 64) { BWs[t] = BW[t]; wf2s[t] = W_f2[t]; }
    for (int idx4 = t; idx4 < 512; idx4 += 256) {
        const int ii  = idx4 >> 6;
        const int hc4 = idx4 & 63;
        const int hh  = hc4 >> 4, c4 = (hc4 & 15) * 4;
        ((float4*)&SGs[ii][0])[hc4] =
            *(const float4*)&SG[((b * 4 + hh) * 32 + i0 + ii) * 64 + c4];
    }
    for (int idx = t; idx < 1024; idx += 256) {
        const int hh = idx >> 8, ii = (idx >> 5) & 7, j = idx & 31;
        const int hi = (b * 4 + hh) * 32 + (i0 + ii);
        const int hj = (b * 4 + hh) * 32 + j;
        const float wv  = w_all[hi * 32 + j];
        const float dsd = dotSD[hi * 32 + j];
        const float mu  = (sumS[hi] + wv * sumD[hj]) * (1.f / 64.f);
        const float e2  = (sumS2[hi] + 2.f * wv * dsd + wv * wv * sumD2[hj]) * (1.f / 64.f);
        const float var = fmaxf(e2 - mu * mu, 0.f);
        w_s[hh][ii][j]   = wv;
        mu_s[hh][ii][j]  = mu;
        inv_s[hh][ii][j] = rsqrtf(var + LN_EPS);
    }
    __syncthreads();

    const int w0 = t >> 6;
    const int e  = t & 63;
    const float GW0 = GWs[e],       GW1 = GWs[64 + e];
    const float GW2 = GWs[128 + e], GW3 = GWs[192 + e];
    const float bwr = BWs[e], f2 = wf2s[e];
    const float* DGb = DG + b * H * N * 64;

    for (int jb = 0; jb < 8; jb++) {
        const int j = jb * 4 + w0;
        const float d0 = DGb[(0 * 32 + j) * 64 + e];
        const float d1 = DGb[(1 * 32 + j) * 64 + e];
        const float d2 = DGb[(2 * 32 + j) * 64 + e];
        const float d3 = DGb[(3 * 32 + j) * 64 + e];
        #pragma unroll
        for (int ii = 0; ii < 8; ii++) {
            float z = bwr;
            z += inv_s[0][ii][j] * (SGs[ii][e]       + w_s[0][ii][j] * d0 - mu_s[0][ii][j] * GW0);
            z += inv_s[1][ii][j] * (SGs[ii][64 + e]  + w_s[1][ii][j] * d1 - mu_s[1][ii][j] * GW1);
            z += inv_s[2][ii][j] * (SGs[ii][128 + e] + w_s[2][ii][j] * d2 - mu_s[2][ii][j] * GW2);
            z += inv_s[3][ii][j] * (SGs[ii][192 + e] + w_s[3][ii][j] * d3 - mu_s[3][ii][j] * GW3);
            float p = leaky(z) * f2;
            #pragma unroll
            for (int m = 32; m; m >>= 1) p += __shfl_xor(p, m);
            if (e == 0) value[(b * 32 + i0 + ii) * 32 + j] = p;
        }
    }
}

extern "C" void kernel_launch(void* const* d_in, const int* in_sizes, int n_in,
                              void* d_out, int out_size, void* d_ws, size_t ws_size,
                              hipStream_t stream)
{
    const float* states   = (const float*)d_in[0];
    const float* policies = (const float*)d_in[1];
    const float* actions  = (const float*)d_in[2];
    const float* W_se     = (const float*)d_in[3];
    const float* b_se     = (const float*)d_in[4];
    const float* W_sape   = (const float*)d_in[5];
    const float* b_sape   = (const float*)d_in[6];
    const float* Wk       = (const float*)d_in[7];
    const float* Wq       = (const float*)d_in[8];
    const float* Wv       = (const float*)d_in[9];
    const float* ln_g     = (const float*)d_in[10];
    const float* ln_b     = (const float*)d_in[11];
    const float* W_f1     = (const float*)d_in[12];
    const float* W_f2     = (const float*)d_in[13];

    float* out_value = (float*)d_out;
    float* out_w     = out_value + B * N * N;

    float* ws    = (float*)d_ws;
    float* SG    = ws;                       // 1,048,576
    float* DG    = SG    + 1048576;          // 1,048,576
    float* sumS  = DG    + 1048576;          // 16,384
    float* sumS2 = sumS  + 16384;
    float* sumD  = sumS2 + 16384;
    float* sumD2 = sumD  + 16384;
    float* dotSD = sumD2 + 16384;            // 524,288
    float* GW    = dotSD + 524288;           // 256
    float* BW    = GW    + 256;              // 64
    u16*   wTb   = (u16*)(BW + 64);          // 98,304
    u16*   wseT  = wTb   + 98304;            // 16,384
    u16*   wsapeT= wseT  + 16384;            // 16,384
    u16*   sapeTail = wsapeT + 16384;        // 4,096
    u16*   wTg   = sapeTail + 4096;          // 16,384

    kP<<<7, 256, 0, stream>>>(Wk, Wq, Wv, W_se, W_sape, ln_g, ln_b, W_f1,
                              wTb, wseT, wsapeT, sapeTail, wTg, GW, BW);
    kB<<<B * H, 1024, 0, stream>>>(states, actions, policies, b_se, b_sape,
                                   wTb, wseT, wsapeT, sapeTail, wTg, out_w,
                                   SG, DG, sumS, sumS2, sumD, sumD2, dotSD);
    kC<<<512, 256, 0, stream>>>(SG, DG, sumS, sumS2, sumD, sumD2, dotSD,
                                out_w, GW, BW, W_f2, out_value);
}